// Round 7
// baseline (328.647 us; speedup 1.0000x reference)
//
#include <hip/hip_runtime.h>
#include <hip/hip_bf16.h>
#include <math.h>

#define NN 100000
#define EE 600000
#define FF 64
#define HH 128
#define CHUNK 1024
#define NCHUNK ((NN + CHUNK - 1) / CHUNK)   // 98
#define NCHUNKS_M (NN / 16)                 // 6250 (exact)

typedef unsigned short u16;
typedef __attribute__((ext_vector_type(8))) short bf16x8;
typedef __attribute__((ext_vector_type(4))) float f32x4;
typedef __attribute__((ext_vector_type(4))) unsigned short us4;
typedef __attribute__((ext_vector_type(4))) float f4;

__device__ __forceinline__ u16 f2bf(float f) {
    __hip_bfloat16 h = __float2bfloat16(f);
    return *(u16*)&h;
}
__device__ __forceinline__ float bf2f(u16 u) {
    unsigned int t = ((unsigned int)u) << 16;
    return *(float*)&t;
}

// ---------------- CSR build ----------------

__global__ void count_k(const int* __restrict__ col, int* __restrict__ cnt) {
    int e = blockIdx.x * 256 + threadIdx.x;
    if (e < EE) atomicAdd(&cnt[__builtin_nontemporal_load(&col[e])], 1);
}

// chunk sums + dinv1 fused
__global__ void chunksum_k(const int* __restrict__ cnt, int* __restrict__ chunk_sum,
                           float* __restrict__ dinv1) {
    int b = blockIdx.x, t = threadIdx.x;
    int base = b * CHUNK + t * 4;
    int s = 0;
    #pragma unroll
    for (int i = 0; i < 4; i++) {
        int idx = base + i;
        if (idx < NN) {
            int cv = cnt[idx];
            s += cv;
            dinv1[idx] = rsqrtf((float)cv + 1.0f);
        }
    }
    __shared__ int sm[4];
    for (int d = 32; d > 0; d >>= 1) s += __shfl_down(s, d);
    if ((t & 63) == 0) sm[t >> 6] = s;
    __syncthreads();
    if (t == 0) chunk_sum[b] = sm[0] + sm[1] + sm[2] + sm[3];
}

__global__ void chunkoff_k(const int* __restrict__ chunk_sum, int* __restrict__ chunk_off,
                           int* __restrict__ col_ptr) {
    if (threadIdx.x == 0) {
        int run = 0;
        for (int i = 0; i < NCHUNK; i++) { chunk_off[i] = run; run += chunk_sum[i]; }
        col_ptr[NN] = run;   // == EE
    }
}

__global__ void colptr_k(const int* __restrict__ cnt, const int* __restrict__ chunk_off,
                         int* __restrict__ col_ptr) {
    int b = blockIdx.x, t = threadIdx.x;
    int base = b * CHUNK + t * 4;
    int c[4]; int tot = 0;
    #pragma unroll
    for (int i = 0; i < 4; i++) { int idx = base + i; c[i] = (idx < NN) ? cnt[idx] : 0; tot += c[i]; }
    __shared__ int s[256];
    s[t] = tot;
    __syncthreads();
    for (int d = 1; d < 256; d <<= 1) {
        int v = (t >= d) ? s[t - d] : 0;
        __syncthreads();
        s[t] += v;
        __syncthreads();
    }
    int excl = s[t] - tot;
    int off = chunk_off[b] + excl;
    int pre = 0;
    #pragma unroll
    for (int i = 0; i < 4; i++) {
        int idx = base + i;
        if (idx < NN) col_ptr[idx] = off + pre;
        pre += c[i];
    }
}

// fill CSR; also precompute layer-1 edge weight dinv1[r]*dinv1[c]
__global__ void fill_k(const int* __restrict__ row, const int* __restrict__ col,
                       const int* __restrict__ col_ptr, int* __restrict__ cursor,
                       const float* __restrict__ dinv1, int* __restrict__ csr_src,
                       float* __restrict__ csr_w) {
    int e = blockIdx.x * 256 + threadIdx.x;
    if (e < EE) {
        int r = __builtin_nontemporal_load(&row[e]);
        int c = __builtin_nontemporal_load(&col[e]);
        int slot = col_ptr[c] + atomicAdd(&cursor[c], 1);
        csr_src[slot] = r;
        csr_w[slot] = dinv1[r] * dinv1[c];
    }
}

// ---------------- fused prep: weight transpose+cast, gemv, x cast ----------------

__global__ void prep_k(const float* __restrict__ W0, const float* __restrict__ W1,
                       const float* __restrict__ W2, const float* __restrict__ Wr,
                       const float* __restrict__ Wg, const float* __restrict__ att_src,
                       const float* __restrict__ att_dst, const float* __restrict__ x,
                       u16* __restrict__ Wt0, u16* __restrict__ Wt1,
                       u16* __restrict__ Wt2, u16* __restrict__ Wtr,
                       float* __restrict__ vs, float* __restrict__ vd,
                       u16* __restrict__ xb) {
    int i = blockIdx.x * 256 + threadIdx.x;
    if (i < NN * FF / 4) {          // cast x -> bf16 (float4 granular)
        f4 v = __builtin_nontemporal_load(&((const f4*)x)[i]);
        us4 o;
        o.x = f2bf(v.x); o.y = f2bf(v.y); o.z = f2bf(v.z); o.w = f2bf(v.w);
        __builtin_nontemporal_store(o, &((us4*)xb)[i]);
        return;
    }
    i -= NN * FF / 4;
    if (i < 8192) {                 // Wt0: [128][64] from W0[64][128]
        int n = i >> 6, k = i & 63;
        Wt0[i] = f2bf(W0[k * 128 + n]);
        return;
    }
    i -= 8192;
    if (i < 16384) {                // Wt1: [128][128]
        int n = i >> 7, k = i & 127;
        Wt1[i] = f2bf(W1[k * 128 + n]);
        return;
    }
    i -= 16384;
    if (i < 16384) {                // Wt2: [128][128]
        int n = i >> 7, k = i & 127;
        Wt2[i] = f2bf(W2[k * 128 + n]);
        return;
    }
    i -= 16384;
    if (i < 8192) {                 // Wtr: [64][128] from Wr[128][64]
        int n = i >> 7, k = i & 127;
        Wtr[i] = f2bf(Wr[k * 64 + n]);
        return;
    }
    i -= 8192;
    if (i < HH) {                   // gemv: vs/vd = Wg @ att_{src,dst}
        float s1 = 0.f, s2 = 0.f;
        for (int j = 0; j < HH; j++) {
            float w = Wg[i * HH + j];
            s1 += w * att_src[j];
            s2 += w * att_dst[j];
        }
        vs[i] = s1;
        vd[i] = s2;
    }
}

// ---------------- layer-1 aggregate in x-space: 64 ch, quarter-wave, 8 edges in flight ----------------

__global__ __launch_bounds__(256) void aggx_k(
    const u16* __restrict__ xb, const int* __restrict__ col_ptr, const int* __restrict__ csr_src,
    const float* __restrict__ csr_w, const float* __restrict__ dinv1, u16* __restrict__ xout) {
    int wid = threadIdx.x >> 6, lane = threadIdx.x & 63;
    int c = blockIdx.x * 4 + wid;
    if (c >= NN) return;
    int q = lane >> 4;           // quarter 0..3
    int ch = (lane & 15) << 2;   // channel base 0..60
    int beg = col_ptr[c], end = col_ptr[c + 1];
    float4 acc = make_float4(0.f, 0.f, 0.f, 0.f);

    int pA = beg + q, pB = pA + 4;
    int rA = 0, rB = 0; float wA = 0.f, wB = 0.f;
    if (pA < end) { rA = __builtin_nontemporal_load(&csr_src[pA]); wA = __builtin_nontemporal_load(&csr_w[pA]); }
    if (pB < end) { rB = __builtin_nontemporal_load(&csr_src[pB]); wB = __builtin_nontemporal_load(&csr_w[pB]); }
    while (pA < end) {
        bool hb = pB < end;
        us4 vA = *(const us4*)&xb[(size_t)rA * FF + ch];
        us4 vB;
        if (hb) vB = *(const us4*)&xb[(size_t)rB * FF + ch];
        int pA2 = pA + 8, pB2 = pB + 8;
        int rA2 = 0, rB2 = 0; float wA2 = 0.f, wB2 = 0.f;
        if (pA2 < end) { rA2 = __builtin_nontemporal_load(&csr_src[pA2]); wA2 = __builtin_nontemporal_load(&csr_w[pA2]); }
        if (pB2 < end) { rB2 = __builtin_nontemporal_load(&csr_src[pB2]); wB2 = __builtin_nontemporal_load(&csr_w[pB2]); }
        acc.x += bf2f(vA.x) * wA;
        acc.y += bf2f(vA.y) * wA;
        acc.z += bf2f(vA.z) * wA;
        acc.w += bf2f(vA.w) * wA;
        if (hb) {
            acc.x += bf2f(vB.x) * wB;
            acc.y += bf2f(vB.y) * wB;
            acc.z += bf2f(vB.z) * wB;
            acc.w += bf2f(vB.w) * wB;
        }
        pA = pA2; pB = pB2; rA = rA2; rB = rB2; wA = wA2; wB = wB2;
    }
    // combine quarters
    acc.x += __shfl_xor(acc.x, 16); acc.y += __shfl_xor(acc.y, 16);
    acc.z += __shfl_xor(acc.z, 16); acc.w += __shfl_xor(acc.w, 16);
    acc.x += __shfl_xor(acc.x, 32); acc.y += __shfl_xor(acc.y, 32);
    acc.z += __shfl_xor(acc.z, 32); acc.w += __shfl_xor(acc.w, 32);

    if (q == 0) {
        us4 v = *(const us4*)&xb[(size_t)c * FF + ch];
        float dc = dinv1[c];
        float ws = dc * dc;
        acc.x = fmaf(bf2f(v.x), ws, acc.x);
        acc.y = fmaf(bf2f(v.y), ws, acc.y);
        acc.z = fmaf(bf2f(v.z), ws, acc.z);
        acc.w = fmaf(bf2f(v.w), ws, acc.w);
        us4 o;
        o.x = f2bf(acc.x); o.y = f2bf(acc.y); o.z = f2bf(acc.z); o.w = f2bf(acc.w);
        __builtin_nontemporal_store(o, (us4*)&xout[(size_t)c * FF + ch]);
    }
}

// ---------------- GEMM1: x1 = relu(xagg @ W0 + b0), fused a_s/a_d ----------------

__global__ __launch_bounds__(256) void gemm1_k(const u16* __restrict__ A, const u16* __restrict__ Wt,
                                               const float* __restrict__ bias,
                                               const float* __restrict__ vs, const float* __restrict__ vd,
                                               u16* __restrict__ C, float* __restrict__ a_s,
                                               float* __restrict__ a_d) {
    constexpr int K = FF, N = HH, KK = K / 32, NT = N / 16;
    int lane = threadIdx.x & 63;
    int l15 = lane & 15, l4 = lane >> 4;
    int wg = blockIdx.x * 4 + (threadIdx.x >> 6);
    int nwaves = gridDim.x * 4;

    bf16x8 a_frag[KK][NT];
    #pragma unroll
    for (int kk = 0; kk < KK; kk++)
        #pragma unroll
        for (int nt = 0; nt < NT; nt++)
            a_frag[kk][nt] = *(const bf16x8*)&Wt[(size_t)(nt * 16 + l15) * K + kk * 32 + l4 * 8];
    f32x4 bias_f[NT], vs_f[NT], vd_f[NT];
    #pragma unroll
    for (int nt = 0; nt < NT; nt++) {
        bias_f[nt] = *(const f32x4*)&bias[nt * 16 + l4 * 4];
        vs_f[nt] = *(const f32x4*)&vs[nt * 16 + l4 * 4];
        vd_f[nt] = *(const f32x4*)&vd[nt * 16 + l4 * 4];
    }

    for (int ch = wg; ch < NCHUNKS_M; ch += nwaves) {
        int row = ch * 16 + l15;
        bf16x8 b_frag[KK];
        #pragma unroll
        for (int kk = 0; kk < KK; kk++)
            b_frag[kk] = __builtin_nontemporal_load((const bf16x8*)&A[(size_t)row * K + kk * 32 + l4 * 8]);
        f32x4 acc[NT] = {};
        #pragma unroll
        for (int kk = 0; kk < KK; kk++)
            #pragma unroll
            for (int nt = 0; nt < NT; nt++)
                acc[nt] = __builtin_amdgcn_mfma_f32_16x16x32_bf16(a_frag[kk][nt], b_frag[kk],
                                                                  acc[nt], 0, 0, 0);
        float s1 = 0.f, s2 = 0.f;
        #pragma unroll
        for (int nt = 0; nt < NT; nt++) {
            float o0 = fmaxf(acc[nt][0] + bias_f[nt][0], 0.f);
            float o1 = fmaxf(acc[nt][1] + bias_f[nt][1], 0.f);
            float o2 = fmaxf(acc[nt][2] + bias_f[nt][2], 0.f);
            float o3 = fmaxf(acc[nt][3] + bias_f[nt][3], 0.f);
            us4 o;
            o.x = f2bf(o0); o.y = f2bf(o1); o.z = f2bf(o2); o.w = f2bf(o3);
            __builtin_nontemporal_store(o, (us4*)&C[(size_t)row * N + nt * 16 + l4 * 4]);
            s1 += o0 * vs_f[nt][0] + o1 * vs_f[nt][1] + o2 * vs_f[nt][2] + o3 * vs_f[nt][3];
            s2 += o0 * vd_f[nt][0] + o1 * vd_f[nt][1] + o2 * vd_f[nt][2] + o3 * vd_f[nt][3];
        }
        s1 += __shfl_xor(s1, 16); s1 += __shfl_xor(s1, 32);
        s2 += __shfl_xor(s2, 16); s2 += __shfl_xor(s2, 32);
        if (l4 == 0) {
            a_s[row] = s1;
            a_d[row] = s2;
        }
    }
}

// ---------------- MFMA GEMM (layers 2/3 + readout) ----------------

template <int K, int N, bool OUTF32>
__global__ __launch_bounds__(256) void mfma_gemm_k(const u16* __restrict__ A,
                                                   const u16* __restrict__ Wt,
                                                   const float* __restrict__ bias,
                                                   void* __restrict__ C_) {
    constexpr int KK = K / 32;
    constexpr int NT = N / 16;
    int lane = threadIdx.x & 63;
    int l15 = lane & 15, l4 = lane >> 4;
    int wg = blockIdx.x * 4 + (threadIdx.x >> 6);
    int nwaves = gridDim.x * 4;

    bf16x8 a_frag[KK][NT];
    #pragma unroll
    for (int kk = 0; kk < KK; kk++)
        #pragma unroll
        for (int nt = 0; nt < NT; nt++)
            a_frag[kk][nt] = *(const bf16x8*)&Wt[(size_t)(nt * 16 + l15) * K + kk * 32 + l4 * 8];

    f32x4 bias_f[NT];
    if (OUTF32) {
        #pragma unroll
        for (int nt = 0; nt < NT; nt++)
            bias_f[nt] = *(const f32x4*)&bias[nt * 16 + l4 * 4];
    }

    float* Cf = (float*)C_;
    u16* Cb = (u16*)C_;

    for (int ch = wg; ch < NCHUNKS_M; ch += nwaves) {
        int row = ch * 16 + l15;
        bf16x8 b_frag[KK];
        #pragma unroll
        for (int kk = 0; kk < KK; kk++)
            b_frag[kk] = __builtin_nontemporal_load((const bf16x8*)&A[(size_t)row * K + kk * 32 + l4 * 8]);
        f32x4 acc[NT] = {};
        #pragma unroll
        for (int kk = 0; kk < KK; kk++)
            #pragma unroll
            for (int nt = 0; nt < NT; nt++)
                acc[nt] = __builtin_amdgcn_mfma_f32_16x16x32_bf16(a_frag[kk][nt], b_frag[kk],
                                                                  acc[nt], 0, 0, 0);
        #pragma unroll
        for (int nt = 0; nt < NT; nt++) {
            int col = nt * 16 + l4 * 4;
            if (OUTF32) {
                f4 o;
                o.x = acc[nt][0] + bias_f[nt][0];
                o.y = acc[nt][1] + bias_f[nt][1];
                o.z = acc[nt][2] + bias_f[nt][2];
                o.w = acc[nt][3] + bias_f[nt][3];
                __builtin_nontemporal_store(o, (f4*)&Cf[(size_t)row * N + col]);
            } else {
                us4 o;
                o.x = f2bf(acc[nt][0]);
                o.y = f2bf(acc[nt][1]);
                o.z = f2bf(acc[nt][2]);
                o.w = f2bf(acc[nt][3]);
                __builtin_nontemporal_store(o, (us4*)&Cb[(size_t)row * N + col]);
            }
        }
    }
}

// ---------------- attention: 8 lanes per node, online softmax ----------------
// writes alpha[p] = softmax * dinv2[c]  (dinv2[r] applied by w2_k)

__global__ __launch_bounds__(256) void attn_k(const int* __restrict__ col_ptr,
                                              const int* __restrict__ csr_src,
                                              const float* __restrict__ a_s,
                                              const float* __restrict__ a_d,
                                              float* __restrict__ alpha,
                                              float* __restrict__ dinv2) {
    int lane = threadIdx.x & 63, wid = threadIdx.x >> 6;
    int grp = lane >> 3, idx = lane & 7;
    int c = blockIdx.x * 32 + wid * 8 + grp;
    if (c >= NN) return;
    int beg = col_ptr[c], end = col_ptr[c + 1];
    float ad = a_d[c];
    float es = a_s[c] + ad;
    es = (es > 0.f) ? es : 0.2f * es;
    float m = (idx == 0) ? es : -1e30f;
    float s = (idx == 0) ? 1.f : 0.f;
    for (int p = beg + idx; p < end; p += 8) {
        float e = a_s[csr_src[p]] + ad;
        e = (e > 0.f) ? e : 0.2f * e;
        alpha[p] = e;
        float mn = fmaxf(m, e);
        s = s * expf(m - mn) + expf(e - mn);
        m = mn;
    }
    #pragma unroll
    for (int d = 1; d < 8; d <<= 1) {
        float mo = __shfl_xor(m, d);
        float so = __shfl_xor(s, d);
        float mn = fmaxf(m, mo);
        s = s * expf(m - mn) + so * expf(mo - mn);
        m = mn;
    }
    float inv = 1.f / s;
    float aself = expf(es - m) * inv;
    float d2 = rsqrtf(2.f - aself);
    if (idx == 0) dinv2[c] = d2;
    float sc = inv * d2;
    for (int p = beg + idx; p < end; p += 8)
        alpha[p] = expf(alpha[p] - m) * sc;
}

// alpha[p] *= dinv2[src]   (completes w = dinv2[r]*alpha*dinv2[c])
__global__ void w2_k(const int* __restrict__ csr_src, const float* __restrict__ dinv2,
                     float* __restrict__ alpha) {
    int p = blockIdx.x * 256 + threadIdx.x;
    if (p < EE) alpha[p] *= dinv2[__builtin_nontemporal_load(&csr_src[p])];
}

// ---------------- layers 2/3 aggregate: 128 ch, half-wave x 4 streams ----------------

__global__ __launch_bounds__(256) void agg2_k(
    const u16* __restrict__ xw, const int* __restrict__ col_ptr, const int* __restrict__ csr_src,
    const float* __restrict__ w2, const float* __restrict__ dinv2, const float* __restrict__ bias,
    u16* __restrict__ xout) {
    int wid = threadIdx.x >> 6, lane = threadIdx.x & 63;
    int c = blockIdx.x * 4 + wid;
    if (c >= NN) return;
    int half = lane >> 5;
    int ch = (lane & 31) << 2;
    int beg = col_ptr[c], end = col_ptr[c + 1];
    float4 acc = make_float4(0.f, 0.f, 0.f, 0.f);

    int pA = beg + half, pB = pA + 2, pC = pA + 4, pD = pA + 6;
    int rA = 0, rB = 0, rC = 0, rD = 0;
    float wA = 0.f, wB = 0.f, wC = 0.f, wD = 0.f;
    if (pA < end) { rA = __builtin_nontemporal_load(&csr_src[pA]); wA = __builtin_nontemporal_load(&w2[pA]); }
    if (pB < end) { rB = __builtin_nontemporal_load(&csr_src[pB]); wB = __builtin_nontemporal_load(&w2[pB]); }
    if (pC < end) { rC = __builtin_nontemporal_load(&csr_src[pC]); wC = __builtin_nontemporal_load(&w2[pC]); }
    if (pD < end) { rD = __builtin_nontemporal_load(&csr_src[pD]); wD = __builtin_nontemporal_load(&w2[pD]); }
    while (pA < end) {
        bool hb = pB < end, hc = pC < end, hd = pD < end;
        us4 vA = *(const us4*)&xw[(size_t)rA * HH + ch];
        us4 vB, vC, vD;
        if (hb) vB = *(const us4*)&xw[(size_t)rB * HH + ch];
        if (hc) vC = *(const us4*)&xw[(size_t)rC * HH + ch];
        if (hd) vD = *(const us4*)&xw[(size_t)rD * HH + ch];
        int pA2 = pA + 8, pB2 = pB + 8, pC2 = pC + 8, pD2 = pD + 8;
        int rA2 = 0, rB2 = 0, rC2 = 0, rD2 = 0;
        float wA2 = 0.f, wB2 = 0.f, wC2 = 0.f, wD2 = 0.f;
        if (pA2 < end) { rA2 = __builtin_nontemporal_load(&csr_src[pA2]); wA2 = __builtin_nontemporal_load(&w2[pA2]); }
        if (pB2 < end) { rB2 = __builtin_nontemporal_load(&csr_src[pB2]); wB2 = __builtin_nontemporal_load(&w2[pB2]); }
        if (pC2 < end) { rC2 = __builtin_nontemporal_load(&csr_src[pC2]); wC2 = __builtin_nontemporal_load(&w2[pC2]); }
        if (pD2 < end) { rD2 = __builtin_nontemporal_load(&csr_src[pD2]); wD2 = __builtin_nontemporal_load(&w2[pD2]); }
        acc.x += bf2f(vA.x) * wA;
        acc.y += bf2f(vA.y) * wA;
        acc.z += bf2f(vA.z) * wA;
        acc.w += bf2f(vA.w) * wA;
        if (hb) {
            acc.x += bf2f(vB.x) * wB;
            acc.y += bf2f(vB.y) * wB;
            acc.z += bf2f(vB.z) * wB;
            acc.w += bf2f(vB.w) * wB;
        }
        if (hc) {
            acc.x += bf2f(vC.x) * wC;
            acc.y += bf2f(vC.y) * wC;
            acc.z += bf2f(vC.z) * wC;
            acc.w += bf2f(vC.w) * wC;
        }
        if (hd) {
            acc.x += bf2f(vD.x) * wD;
            acc.y += bf2f(vD.y) * wD;
            acc.z += bf2f(vD.z) * wD;
            acc.w += bf2f(vD.w) * wD;
        }
        pA = pA2; pB = pB2; pC = pC2; pD = pD2;
        rA = rA2; rB = rB2; rC = rC2; rD = rD2;
        wA = wA2; wB = wB2; wC = wC2; wD = wD2;
    }
    acc.x += __shfl_xor(acc.x, 32);
    acc.y += __shfl_xor(acc.y, 32);
    acc.z += __shfl_xor(acc.z, 32);
    acc.w += __shfl_xor(acc.w, 32);

    if (half == 0) {
        us4 v = *(const us4*)&xw[(size_t)c * HH + ch];
        float dc = dinv2[c];
        float ws = dc * dc;
        float4 b4 = *(const float4*)&bias[ch];
        acc.x = fmaxf(fmaf(bf2f(v.x), ws, acc.x) + b4.x, 0.f);
        acc.y = fmaxf(fmaf(bf2f(v.y), ws, acc.y) + b4.y, 0.f);
        acc.z = fmaxf(fmaf(bf2f(v.z), ws, acc.z) + b4.z, 0.f);
        acc.w = fmaxf(fmaf(bf2f(v.w), ws, acc.w) + b4.w, 0.f);
        us4 o;
        o.x = f2bf(acc.x); o.y = f2bf(acc.y); o.z = f2bf(acc.z); o.w = f2bf(acc.w);
        __builtin_nontemporal_store(o, (us4*)&xout[(size_t)c * HH + ch]);
    }
}

// ---------------- launch ----------------

extern "C" void kernel_launch(void* const* d_in, const int* in_sizes, int n_in,
                              void* d_out, int out_size, void* d_ws, size_t ws_size,
                              hipStream_t stream) {
    const float* x = (const float*)d_in[0];
    const int* eidx = (const int*)d_in[1];     // [2][E]: row, col
    const float* W0 = (const float*)d_in[3];
    const float* b0 = (const float*)d_in[4];
    const float* Wg = (const float*)d_in[5];
    const float* att_src = (const float*)d_in[6];
    const float* att_dst = (const float*)d_in[7];
    const float* W1 = (const float*)d_in[8];
    const float* b1 = (const float*)d_in[9];
    const float* W2 = (const float*)d_in[10];
    const float* b2 = (const float*)d_in[11];
    const float* Wr = (const float*)d_in[12];
    const float* br = (const float*)d_in[13];
    float* out = (float*)d_out;

    const int* erow = eidx;
    const int* ecol = eidx + EE;

    char* p = (char*)d_ws;
    auto alloc = [&](size_t bytes) {
        void* r = (void*)p;
        p += (bytes + 255) & ~(size_t)255;
        return r;
    };
    int* col_ptr = (int*)alloc((NN + 1) * sizeof(int));
    int* csr_src = (int*)alloc(EE * sizeof(int));
    float* csr_w = (float*)alloc(EE * sizeof(float));
    int* cnt = (int*)alloc(NN * sizeof(int));
    int* cursor = (int*)alloc(NN * sizeof(int));
    int* chunk_sum = (int*)alloc(128 * sizeof(int));
    int* chunk_off = (int*)alloc(128 * sizeof(int));
    float* alpha = (float*)alloc(EE * sizeof(float));
    float* dinv1 = (float*)alloc(NN * sizeof(float));
    float* dinv2 = (float*)alloc(NN * sizeof(float));
    float* a_s = (float*)alloc(NN * sizeof(float));
    float* a_d = (float*)alloc(NN * sizeof(float));
    float* vs = (float*)alloc(HH * sizeof(float));
    float* vd = (float*)alloc(HH * sizeof(float));
    u16* Wt0 = (u16*)alloc(8192 * sizeof(u16));    // [128][64]
    u16* Wt1 = (u16*)alloc(16384 * sizeof(u16));   // [128][128]
    u16* Wt2 = (u16*)alloc(16384 * sizeof(u16));   // [128][128]
    u16* Wtr = (u16*)alloc(8192 * sizeof(u16));    // [64][128]
    u16* xb = (u16*)alloc((size_t)NN * FF * sizeof(u16));     // bf16(x)
    u16* xaggb = (u16*)alloc((size_t)NN * FF * sizeof(u16));  // bf16(Â x)
    u16* bufA = (u16*)alloc((size_t)NN * HH * sizeof(u16));
    u16* bufB = (u16*)alloc((size_t)NN * HH * sizeof(u16));

    hipMemsetAsync(cnt, 0, NN * sizeof(int), stream);
    hipMemsetAsync(cursor, 0, NN * sizeof(int), stream);

    count_k<<<(EE + 255) / 256, 256, 0, stream>>>(ecol, cnt);
    chunksum_k<<<NCHUNK, 256, 0, stream>>>(cnt, chunk_sum, dinv1);
    chunkoff_k<<<1, 64, 0, stream>>>(chunk_sum, chunk_off, col_ptr);
    colptr_k<<<NCHUNK, 256, 0, stream>>>(cnt, chunk_off, col_ptr);
    fill_k<<<(EE + 255) / 256, 256, 0, stream>>>(erow, ecol, col_ptr, cursor, dinv1,
                                                 csr_src, csr_w);
    // prep: x cast + weight transpose/cast + gemv  (1,649,280 work items)
    prep_k<<<(NN * FF / 4 + 49280 + 255) / 256, 256, 0, stream>>>(
        W0, W1, W2, Wr, Wg, att_src, att_dst, x, Wt0, Wt1, Wt2, Wtr, vs, vd, xb);

    int aggGrid = (NN + 3) / 4;
    const int GG = 512;

    // layer 1: xagg = Â1 x ; x1 = relu(xagg@W0+b0) + fused a_s/a_d
    aggx_k<<<aggGrid, 256, 0, stream>>>(xb, col_ptr, csr_src, csr_w, dinv1, xaggb);
    gemm1_k<<<GG, 256, 0, stream>>>(xaggb, Wt0, b0, vs, vd, bufA, a_s, a_d);
    // attention
    attn_k<<<(NN + 31) / 32, 256, 0, stream>>>(col_ptr, csr_src, a_s, a_d, alpha, dinv2);
    w2_k<<<(EE + 255) / 256, 256, 0, stream>>>(csr_src, dinv2, alpha);
    // layer 2
    mfma_gemm_k<HH, HH, false><<<GG, 256, 0, stream>>>(bufA, Wt1, nullptr, bufB);
    agg2_k<<<aggGrid, 256, 0, stream>>>(bufB, col_ptr, csr_src, alpha, dinv2, b1, bufA);
    // layer 3
    mfma_gemm_k<HH, HH, false><<<GG, 256, 0, stream>>>(bufA, Wt2, nullptr, bufB);
    agg2_k<<<aggGrid, 256, 0, stream>>>(bufB, col_ptr, csr_src, alpha, dinv2, b2, bufA);
    // readout
    mfma_gemm_k<HH, FF, true><<<GG, 256, 0, stream>>>(bufA, Wtr, br, out);
}

// Round 8
// 297.580 us; speedup vs baseline: 1.1044x; 1.1044x over previous
//
#include <hip/hip_runtime.h>
#include <hip/hip_bf16.h>
#include <math.h>

#define NN 100000
#define EE 600000
#define FF 64
#define HH 128
#define CHUNK 1024
#define NCHUNK ((NN + CHUNK - 1) / CHUNK)   // 98
#define NCHUNKS_M (NN / 16)                 // 6250 (exact)

typedef unsigned short u16;
typedef __attribute__((ext_vector_type(8))) short bf16x8;
typedef __attribute__((ext_vector_type(4))) float f32x4;

__device__ __forceinline__ u16 f2bf(float f) {
    __hip_bfloat16 h = __float2bfloat16(f);
    return *(u16*)&h;
}
__device__ __forceinline__ float bf2f(u16 u) {
    unsigned int t = ((unsigned int)u) << 16;
    return *(float*)&t;
}

// ---------------- CSR build ----------------

__global__ void count_k(const int* __restrict__ col, int* __restrict__ cnt) {
    int e = blockIdx.x * 256 + threadIdx.x;
    if (e < EE) atomicAdd(&cnt[col[e]], 1);
}

// chunk sums + dinv1 fused
__global__ void chunksum_k(const int* __restrict__ cnt, int* __restrict__ chunk_sum,
                           float* __restrict__ dinv1) {
    int b = blockIdx.x, t = threadIdx.x;
    int base = b * CHUNK + t * 4;
    int s = 0;
    #pragma unroll
    for (int i = 0; i < 4; i++) {
        int idx = base + i;
        if (idx < NN) {
            int cv = cnt[idx];
            s += cv;
            dinv1[idx] = rsqrtf((float)cv + 1.0f);
        }
    }
    __shared__ int sm[4];
    for (int d = 32; d > 0; d >>= 1) s += __shfl_down(s, d);
    if ((t & 63) == 0) sm[t >> 6] = s;
    __syncthreads();
    if (t == 0) chunk_sum[b] = sm[0] + sm[1] + sm[2] + sm[3];
}

__global__ void chunkoff_k(const int* __restrict__ chunk_sum, int* __restrict__ chunk_off,
                           int* __restrict__ col_ptr) {
    if (threadIdx.x == 0) {
        int run = 0;
        for (int i = 0; i < NCHUNK; i++) { chunk_off[i] = run; run += chunk_sum[i]; }
        col_ptr[NN] = run;   // == EE
    }
}

// col_ptr + cursor (cursor starts at col_ptr so fill needs one atomicAdd only)
__global__ void colptr_k(const int* __restrict__ cnt, const int* __restrict__ chunk_off,
                         int* __restrict__ col_ptr, int* __restrict__ cursor) {
    int b = blockIdx.x, t = threadIdx.x;
    int base = b * CHUNK + t * 4;
    int c[4]; int tot = 0;
    #pragma unroll
    for (int i = 0; i < 4; i++) { int idx = base + i; c[i] = (idx < NN) ? cnt[idx] : 0; tot += c[i]; }
    __shared__ int s[256];
    s[t] = tot;
    __syncthreads();
    for (int d = 1; d < 256; d <<= 1) {
        int v = (t >= d) ? s[t - d] : 0;
        __syncthreads();
        s[t] += v;
        __syncthreads();
    }
    int excl = s[t] - tot;
    int off = chunk_off[b] + excl;
    int pre = 0;
    #pragma unroll
    for (int i = 0; i < 4; i++) {
        int idx = base + i;
        if (idx < NN) {
            col_ptr[idx] = off + pre;
            cursor[idx] = off + pre;
        }
        pre += c[i];
    }
}

// fill CSR: csr_src (for attn/w2) + interleaved meta1 = (src, dinv1[r]*dinv1[c])
__global__ void fill_k(const int* __restrict__ row, const int* __restrict__ col,
                       int* __restrict__ cursor, const float* __restrict__ dinv1,
                       int* __restrict__ csr_src, int2* __restrict__ meta1) {
    int e = blockIdx.x * 256 + threadIdx.x;
    if (e < EE) {
        int r = row[e], c = col[e];
        int slot = atomicAdd(&cursor[c], 1);
        csr_src[slot] = r;
        float w = dinv1[r] * dinv1[c];
        meta1[slot] = make_int2(r, __float_as_int(w));
    }
}

// ---------------- fused prep: weight transpose+cast, gemv, x cast ----------------

__global__ void prep_k(const float* __restrict__ W0, const float* __restrict__ W1,
                       const float* __restrict__ W2, const float* __restrict__ Wr,
                       const float* __restrict__ Wg, const float* __restrict__ att_src,
                       const float* __restrict__ att_dst, const float* __restrict__ x,
                       u16* __restrict__ Wt0, u16* __restrict__ Wt1,
                       u16* __restrict__ Wt2, u16* __restrict__ Wtr,
                       float* __restrict__ vs, float* __restrict__ vd,
                       u16* __restrict__ xb) {
    int i = blockIdx.x * 256 + threadIdx.x;
    if (i < NN * FF / 4) {          // cast x -> bf16 (float4 granular)
        float4 v = ((const float4*)x)[i];
        ushort4 o;
        o.x = f2bf(v.x); o.y = f2bf(v.y); o.z = f2bf(v.z); o.w = f2bf(v.w);
        ((ushort4*)xb)[i] = o;
        return;
    }
    i -= NN * FF / 4;
    if (i < 8192) {                 // Wt0: [128][64] from W0[64][128]
        int n = i >> 6, k = i & 63;
        Wt0[i] = f2bf(W0[k * 128 + n]);
        return;
    }
    i -= 8192;
    if (i < 16384) {                // Wt1: [128][128]
        int n = i >> 7, k = i & 127;
        Wt1[i] = f2bf(W1[k * 128 + n]);
        return;
    }
    i -= 16384;
    if (i < 16384) {                // Wt2: [128][128]
        int n = i >> 7, k = i & 127;
        Wt2[i] = f2bf(W2[k * 128 + n]);
        return;
    }
    i -= 16384;
    if (i < 8192) {                 // Wtr: [64][128] from Wr[128][64]
        int n = i >> 7, k = i & 127;
        Wtr[i] = f2bf(Wr[k * 64 + n]);
        return;
    }
    i -= 8192;
    if (i < HH) {                   // gemv: vs/vd = Wg @ att_{src,dst}
        float s1 = 0.f, s2 = 0.f;
        for (int j = 0; j < HH; j++) {
            float w = Wg[i * HH + j];
            s1 += w * att_src[j];
            s2 += w * att_dst[j];
        }
        vs[i] = s1;
        vd[i] = s2;
    }
}

// ---------------- layer-1 aggregate in x-space: 64 ch, quarter-wave, 8 edges in flight ----------------

__global__ __launch_bounds__(256) void aggx_k(
    const u16* __restrict__ xb, const int* __restrict__ col_ptr, const int2* __restrict__ meta1,
    const float* __restrict__ dinv1, u16* __restrict__ xout) {
    int wid = threadIdx.x >> 6, lane = threadIdx.x & 63;
    int c = blockIdx.x * 4 + wid;
    if (c >= NN) return;
    int q = lane >> 4;           // quarter 0..3
    int ch = (lane & 15) << 2;   // channel base 0..60
    int beg = col_ptr[c], end = col_ptr[c + 1];
    float4 acc = make_float4(0.f, 0.f, 0.f, 0.f);

    int pA = beg + q, pB = pA + 4;
    int rA = 0, rB = 0; float wA = 0.f, wB = 0.f;
    if (pA < end) { int2 m = meta1[pA]; rA = m.x; wA = __int_as_float(m.y); }
    if (pB < end) { int2 m = meta1[pB]; rB = m.x; wB = __int_as_float(m.y); }
    while (pA < end) {
        bool hb = pB < end;
        ushort4 vA = *(const ushort4*)&xb[(size_t)rA * FF + ch];
        ushort4 vB;
        if (hb) vB = *(const ushort4*)&xb[(size_t)rB * FF + ch];
        int pA2 = pA + 8, pB2 = pB + 8;
        int rA2 = 0, rB2 = 0; float wA2 = 0.f, wB2 = 0.f;
        if (pA2 < end) { int2 m = meta1[pA2]; rA2 = m.x; wA2 = __int_as_float(m.y); }
        if (pB2 < end) { int2 m = meta1[pB2]; rB2 = m.x; wB2 = __int_as_float(m.y); }
        acc.x += bf2f(vA.x) * wA;
        acc.y += bf2f(vA.y) * wA;
        acc.z += bf2f(vA.z) * wA;
        acc.w += bf2f(vA.w) * wA;
        if (hb) {
            acc.x += bf2f(vB.x) * wB;
            acc.y += bf2f(vB.y) * wB;
            acc.z += bf2f(vB.z) * wB;
            acc.w += bf2f(vB.w) * wB;
        }
        pA = pA2; pB = pB2; rA = rA2; rB = rB2; wA = wA2; wB = wB2;
    }
    // combine quarters
    acc.x += __shfl_xor(acc.x, 16); acc.y += __shfl_xor(acc.y, 16);
    acc.z += __shfl_xor(acc.z, 16); acc.w += __shfl_xor(acc.w, 16);
    acc.x += __shfl_xor(acc.x, 32); acc.y += __shfl_xor(acc.y, 32);
    acc.z += __shfl_xor(acc.z, 32); acc.w += __shfl_xor(acc.w, 32);

    if (q == 0) {
        ushort4 v = *(const ushort4*)&xb[(size_t)c * FF + ch];
        float dc = dinv1[c];
        float ws = dc * dc;
        acc.x = fmaf(bf2f(v.x), ws, acc.x);
        acc.y = fmaf(bf2f(v.y), ws, acc.y);
        acc.z = fmaf(bf2f(v.z), ws, acc.z);
        acc.w = fmaf(bf2f(v.w), ws, acc.w);
        ushort4 o;
        o.x = f2bf(acc.x); o.y = f2bf(acc.y); o.z = f2bf(acc.z); o.w = f2bf(acc.w);
        *(ushort4*)&xout[(size_t)c * FF + ch] = o;
    }
}

// ---------------- GEMM1: x1 = relu(xagg @ W0 + b0), fused a_s/a_d ----------------

__global__ __launch_bounds__(256) void gemm1_k(const u16* __restrict__ A, const u16* __restrict__ Wt,
                                               const float* __restrict__ bias,
                                               const float* __restrict__ vs, const float* __restrict__ vd,
                                               u16* __restrict__ C, float* __restrict__ a_s,
                                               float* __restrict__ a_d) {
    constexpr int K = FF, N = HH, KK = K / 32, NT = N / 16;
    int lane = threadIdx.x & 63;
    int l15 = lane & 15, l4 = lane >> 4;
    int wg = blockIdx.x * 4 + (threadIdx.x >> 6);
    int nwaves = gridDim.x * 4;

    bf16x8 a_frag[KK][NT];
    #pragma unroll
    for (int kk = 0; kk < KK; kk++)
        #pragma unroll
        for (int nt = 0; nt < NT; nt++)
            a_frag[kk][nt] = *(const bf16x8*)&Wt[(size_t)(nt * 16 + l15) * K + kk * 32 + l4 * 8];
    f32x4 bias_f[NT], vs_f[NT], vd_f[NT];
    #pragma unroll
    for (int nt = 0; nt < NT; nt++) {
        bias_f[nt] = *(const f32x4*)&bias[nt * 16 + l4 * 4];
        vs_f[nt] = *(const f32x4*)&vs[nt * 16 + l4 * 4];
        vd_f[nt] = *(const f32x4*)&vd[nt * 16 + l4 * 4];
    }

    for (int ch = wg; ch < NCHUNKS_M; ch += nwaves) {
        int row = ch * 16 + l15;
        bf16x8 b_frag[KK];
        #pragma unroll
        for (int kk = 0; kk < KK; kk++)
            b_frag[kk] = *(const bf16x8*)&A[(size_t)row * K + kk * 32 + l4 * 8];
        f32x4 acc[NT] = {};
        #pragma unroll
        for (int kk = 0; kk < KK; kk++)
            #pragma unroll
            for (int nt = 0; nt < NT; nt++)
                acc[nt] = __builtin_amdgcn_mfma_f32_16x16x32_bf16(a_frag[kk][nt], b_frag[kk],
                                                                  acc[nt], 0, 0, 0);
        float s1 = 0.f, s2 = 0.f;
        #pragma unroll
        for (int nt = 0; nt < NT; nt++) {
            float o0 = fmaxf(acc[nt][0] + bias_f[nt][0], 0.f);
            float o1 = fmaxf(acc[nt][1] + bias_f[nt][1], 0.f);
            float o2 = fmaxf(acc[nt][2] + bias_f[nt][2], 0.f);
            float o3 = fmaxf(acc[nt][3] + bias_f[nt][3], 0.f);
            ushort4 o;
            o.x = f2bf(o0); o.y = f2bf(o1); o.z = f2bf(o2); o.w = f2bf(o3);
            *(ushort4*)&C[(size_t)row * N + nt * 16 + l4 * 4] = o;
            s1 += o0 * vs_f[nt][0] + o1 * vs_f[nt][1] + o2 * vs_f[nt][2] + o3 * vs_f[nt][3];
            s2 += o0 * vd_f[nt][0] + o1 * vd_f[nt][1] + o2 * vd_f[nt][2] + o3 * vd_f[nt][3];
        }
        s1 += __shfl_xor(s1, 16); s1 += __shfl_xor(s1, 32);
        s2 += __shfl_xor(s2, 16); s2 += __shfl_xor(s2, 32);
        if (l4 == 0) {
            a_s[row] = s1;
            a_d[row] = s2;
        }
    }
}

// ---------------- MFMA GEMM (layers 2/3 + readout) ----------------

template <int K, int N, bool OUTF32>
__global__ __launch_bounds__(256) void mfma_gemm_k(const u16* __restrict__ A,
                                                   const u16* __restrict__ Wt,
                                                   const float* __restrict__ bias,
                                                   void* __restrict__ C_) {
    constexpr int KK = K / 32;
    constexpr int NT = N / 16;
    int lane = threadIdx.x & 63;
    int l15 = lane & 15, l4 = lane >> 4;
    int wg = blockIdx.x * 4 + (threadIdx.x >> 6);
    int nwaves = gridDim.x * 4;

    bf16x8 a_frag[KK][NT];
    #pragma unroll
    for (int kk = 0; kk < KK; kk++)
        #pragma unroll
        for (int nt = 0; nt < NT; nt++)
            a_frag[kk][nt] = *(const bf16x8*)&Wt[(size_t)(nt * 16 + l15) * K + kk * 32 + l4 * 8];

    f32x4 bias_f[NT];
    if (OUTF32) {
        #pragma unroll
        for (int nt = 0; nt < NT; nt++)
            bias_f[nt] = *(const f32x4*)&bias[nt * 16 + l4 * 4];
    }

    float* Cf = (float*)C_;
    u16* Cb = (u16*)C_;

    for (int ch = wg; ch < NCHUNKS_M; ch += nwaves) {
        int row = ch * 16 + l15;
        bf16x8 b_frag[KK];
        #pragma unroll
        for (int kk = 0; kk < KK; kk++)
            b_frag[kk] = *(const bf16x8*)&A[(size_t)row * K + kk * 32 + l4 * 8];
        f32x4 acc[NT] = {};
        #pragma unroll
        for (int kk = 0; kk < KK; kk++)
            #pragma unroll
            for (int nt = 0; nt < NT; nt++)
                acc[nt] = __builtin_amdgcn_mfma_f32_16x16x32_bf16(a_frag[kk][nt], b_frag[kk],
                                                                  acc[nt], 0, 0, 0);
        #pragma unroll
        for (int nt = 0; nt < NT; nt++) {
            int col = nt * 16 + l4 * 4;
            if (OUTF32) {
                float4 o;
                o.x = acc[nt][0] + bias_f[nt][0];
                o.y = acc[nt][1] + bias_f[nt][1];
                o.z = acc[nt][2] + bias_f[nt][2];
                o.w = acc[nt][3] + bias_f[nt][3];
                *(float4*)&Cf[(size_t)row * N + col] = o;
            } else {
                ushort4 o;
                o.x = f2bf(acc[nt][0]);
                o.y = f2bf(acc[nt][1]);
                o.z = f2bf(acc[nt][2]);
                o.w = f2bf(acc[nt][3]);
                *(ushort4*)&Cb[(size_t)row * N + col] = o;
            }
        }
    }
}

// ---------------- attention: 8 lanes per node, online softmax ----------------
// writes alpha[p] = softmax * dinv2[c]  (dinv2[r] applied by w2_k)

__global__ __launch_bounds__(256) void attn_k(const int* __restrict__ col_ptr,
                                              const int* __restrict__ csr_src,
                                              const float* __restrict__ a_s,
                                              const float* __restrict__ a_d,
                                              float* __restrict__ alpha,
                                              float* __restrict__ dinv2) {
    int lane = threadIdx.x & 63, wid = threadIdx.x >> 6;
    int grp = lane >> 3, idx = lane & 7;
    int c = blockIdx.x * 32 + wid * 8 + grp;
    if (c >= NN) return;
    int beg = col_ptr[c], end = col_ptr[c + 1];
    float ad = a_d[c];
    float es = a_s[c] + ad;
    es = (es > 0.f) ? es : 0.2f * es;
    float m = (idx == 0) ? es : -1e30f;
    float s = (idx == 0) ? 1.f : 0.f;
    for (int p = beg + idx; p < end; p += 8) {
        float e = a_s[csr_src[p]] + ad;
        e = (e > 0.f) ? e : 0.2f * e;
        alpha[p] = e;
        float mn = fmaxf(m, e);
        s = s * expf(m - mn) + expf(e - mn);
        m = mn;
    }
    #pragma unroll
    for (int d = 1; d < 8; d <<= 1) {
        float mo = __shfl_xor(m, d);
        float so = __shfl_xor(s, d);
        float mn = fmaxf(m, mo);
        s = s * expf(m - mn) + so * expf(mo - mn);
        m = mn;
    }
    float inv = 1.f / s;
    float aself = expf(es - m) * inv;
    float d2 = rsqrtf(2.f - aself);
    if (idx == 0) dinv2[c] = d2;
    float sc = inv * d2;
    for (int p = beg + idx; p < end; p += 8)
        alpha[p] = expf(alpha[p] - m) * sc;
}

// meta2[p] = (src, alpha[p] * dinv2[src])  — completes w = dinv2[r]*alpha*dinv2[c]
__global__ void w2_k(const int* __restrict__ csr_src, const float* __restrict__ dinv2,
                     const float* __restrict__ alpha, int2* __restrict__ meta2) {
    int p = blockIdx.x * 256 + threadIdx.x;
    if (p < EE) {
        int r = csr_src[p];
        float w = alpha[p] * dinv2[r];
        meta2[p] = make_int2(r, __float_as_int(w));
    }
}

// ---------------- layers 2/3 aggregate: 128 ch, half-wave x 3 streams ----------------

__global__ __launch_bounds__(256) void agg2_k(
    const u16* __restrict__ xw, const int* __restrict__ col_ptr, const int2* __restrict__ meta2,
    const float* __restrict__ dinv2, const float* __restrict__ bias, u16* __restrict__ xout) {
    int wid = threadIdx.x >> 6, lane = threadIdx.x & 63;
    int c = blockIdx.x * 4 + wid;
    if (c >= NN) return;
    int half = lane >> 5;
    int ch = (lane & 31) << 2;
    int beg = col_ptr[c], end = col_ptr[c + 1];
    float4 acc = make_float4(0.f, 0.f, 0.f, 0.f);

    int pA = beg + half, pB = pA + 2, pC = pA + 4;
    int rA = 0, rB = 0, rC = 0; float wA = 0.f, wB = 0.f, wC = 0.f;
    if (pA < end) { int2 m = meta2[pA]; rA = m.x; wA = __int_as_float(m.y); }
    if (pB < end) { int2 m = meta2[pB]; rB = m.x; wB = __int_as_float(m.y); }
    if (pC < end) { int2 m = meta2[pC]; rC = m.x; wC = __int_as_float(m.y); }
    while (pA < end) {
        bool hb = pB < end, hc = pC < end;
        ushort4 vA = *(const ushort4*)&xw[(size_t)rA * HH + ch];
        ushort4 vB, vC;
        if (hb) vB = *(const ushort4*)&xw[(size_t)rB * HH + ch];
        if (hc) vC = *(const ushort4*)&xw[(size_t)rC * HH + ch];
        int pA2 = pA + 6, pB2 = pB + 6, pC2 = pC + 6;
        int rA2 = 0, rB2 = 0, rC2 = 0; float wA2 = 0.f, wB2 = 0.f, wC2 = 0.f;
        if (pA2 < end) { int2 m = meta2[pA2]; rA2 = m.x; wA2 = __int_as_float(m.y); }
        if (pB2 < end) { int2 m = meta2[pB2]; rB2 = m.x; wB2 = __int_as_float(m.y); }
        if (pC2 < end) { int2 m = meta2[pC2]; rC2 = m.x; wC2 = __int_as_float(m.y); }
        acc.x += bf2f(vA.x) * wA;
        acc.y += bf2f(vA.y) * wA;
        acc.z += bf2f(vA.z) * wA;
        acc.w += bf2f(vA.w) * wA;
        if (hb) {
            acc.x += bf2f(vB.x) * wB;
            acc.y += bf2f(vB.y) * wB;
            acc.z += bf2f(vB.z) * wB;
            acc.w += bf2f(vB.w) * wB;
        }
        if (hc) {
            acc.x += bf2f(vC.x) * wC;
            acc.y += bf2f(vC.y) * wC;
            acc.z += bf2f(vC.z) * wC;
            acc.w += bf2f(vC.w) * wC;
        }
        pA = pA2; pB = pB2; pC = pC2;
        rA = rA2; rB = rB2; rC = rC2;
        wA = wA2; wB = wB2; wC = wC2;
    }
    acc.x += __shfl_xor(acc.x, 32);
    acc.y += __shfl_xor(acc.y, 32);
    acc.z += __shfl_xor(acc.z, 32);
    acc.w += __shfl_xor(acc.w, 32);

    if (half == 0) {
        ushort4 v = *(const ushort4*)&xw[(size_t)c * HH + ch];
        float dc = dinv2[c];
        float ws = dc * dc;
        float4 b4 = *(const float4*)&bias[ch];
        acc.x = fmaxf(fmaf(bf2f(v.x), ws, acc.x) + b4.x, 0.f);
        acc.y = fmaxf(fmaf(bf2f(v.y), ws, acc.y) + b4.y, 0.f);
        acc.z = fmaxf(fmaf(bf2f(v.z), ws, acc.z) + b4.z, 0.f);
        acc.w = fmaxf(fmaf(bf2f(v.w), ws, acc.w) + b4.w, 0.f);
        ushort4 o;
        o.x = f2bf(acc.x); o.y = f2bf(acc.y); o.z = f2bf(acc.z); o.w = f2bf(acc.w);
        *(ushort4*)&xout[(size_t)c * HH + ch] = o;
    }
}

// ---------------- launch ----------------

extern "C" void kernel_launch(void* const* d_in, const int* in_sizes, int n_in,
                              void* d_out, int out_size, void* d_ws, size_t ws_size,
                              hipStream_t stream) {
    const float* x = (const float*)d_in[0];
    const int* eidx = (const int*)d_in[1];     // [2][E]: row, col
    const float* W0 = (const float*)d_in[3];
    const float* b0 = (const float*)d_in[4];
    const float* Wg = (const float*)d_in[5];
    const float* att_src = (const float*)d_in[6];
    const float* att_dst = (const float*)d_in[7];
    const float* W1 = (const float*)d_in[8];
    const float* b1 = (const float*)d_in[9];
    const float* W2 = (const float*)d_in[10];
    const float* b2 = (const float*)d_in[11];
    const float* Wr = (const float*)d_in[12];
    const float* br = (const float*)d_in[13];
    float* out = (float*)d_out;

    const int* erow = eidx;
    const int* ecol = eidx + EE;

    char* p = (char*)d_ws;
    auto alloc = [&](size_t bytes) {
        void* r = (void*)p;
        p += (bytes + 255) & ~(size_t)255;
        return r;
    };
    int* col_ptr = (int*)alloc((NN + 1) * sizeof(int));
    int* csr_src = (int*)alloc(EE * sizeof(int));
    int2* meta1 = (int2*)alloc(EE * sizeof(int2));
    int2* meta2 = (int2*)alloc(EE * sizeof(int2));
    int* cnt = (int*)alloc(NN * sizeof(int));
    int* cursor = (int*)alloc(NN * sizeof(int));
    int* chunk_sum = (int*)alloc(128 * sizeof(int));
    int* chunk_off = (int*)alloc(128 * sizeof(int));
    float* alpha = (float*)alloc(EE * sizeof(float));
    float* dinv1 = (float*)alloc(NN * sizeof(float));
    float* dinv2 = (float*)alloc(NN * sizeof(float));
    float* a_s = (float*)alloc(NN * sizeof(float));
    float* a_d = (float*)alloc(NN * sizeof(float));
    float* vs = (float*)alloc(HH * sizeof(float));
    float* vd = (float*)alloc(HH * sizeof(float));
    u16* Wt0 = (u16*)alloc(8192 * sizeof(u16));    // [128][64]
    u16* Wt1 = (u16*)alloc(16384 * sizeof(u16));   // [128][128]
    u16* Wt2 = (u16*)alloc(16384 * sizeof(u16));   // [128][128]
    u16* Wtr = (u16*)alloc(8192 * sizeof(u16));    // [64][128]
    u16* xb = (u16*)alloc((size_t)NN * FF * sizeof(u16));     // bf16(x)
    u16* xaggb = (u16*)alloc((size_t)NN * FF * sizeof(u16));  // bf16(Â x)
    u16* bufA = (u16*)alloc((size_t)NN * HH * sizeof(u16));
    u16* bufB = (u16*)alloc((size_t)NN * HH * sizeof(u16));

    hipMemsetAsync(cnt, 0, NN * sizeof(int), stream);

    count_k<<<(EE + 255) / 256, 256, 0, stream>>>(ecol, cnt);
    chunksum_k<<<NCHUNK, 256, 0, stream>>>(cnt, chunk_sum, dinv1);
    chunkoff_k<<<1, 64, 0, stream>>>(chunk_sum, chunk_off, col_ptr);
    colptr_k<<<NCHUNK, 256, 0, stream>>>(cnt, chunk_off, col_ptr, cursor);
    fill_k<<<(EE + 255) / 256, 256, 0, stream>>>(erow, ecol, cursor, dinv1, csr_src, meta1);
    // prep: x cast + weight transpose/cast + gemv
    prep_k<<<(NN * FF / 4 + 49280 + 255) / 256, 256, 0, stream>>>(
        W0, W1, W2, Wr, Wg, att_src, att_dst, x, Wt0, Wt1, Wt2, Wtr, vs, vd, xb);

    int aggGrid = (NN + 3) / 4;
    const int GG = 512;

    // layer 1: xagg = Â1 x ; x1 = relu(xagg@W0+b0) + fused a_s/a_d
    aggx_k<<<aggGrid, 256, 0, stream>>>(xb, col_ptr, meta1, dinv1, xaggb);
    gemm1_k<<<GG, 256, 0, stream>>>(xaggb, Wt0, b0, vs, vd, bufA, a_s, a_d);
    // attention
    attn_k<<<(NN + 31) / 32, 256, 0, stream>>>(col_ptr, csr_src, a_s, a_d, alpha, dinv2);
    w2_k<<<(EE + 255) / 256, 256, 0, stream>>>(csr_src, dinv2, alpha, meta2);
    // layer 2
    mfma_gemm_k<HH, HH, false><<<GG, 256, 0, stream>>>(bufA, Wt1, nullptr, bufB);
    agg2_k<<<aggGrid, 256, 0, stream>>>(bufB, col_ptr, meta2, dinv2, b1, bufA);
    // layer 3
    mfma_gemm_k<HH, HH, false><<<GG, 256, 0, stream>>>(bufA, Wt2, nullptr, bufB);
    agg2_k<<<aggGrid, 256, 0, stream>>>(bufB, col_ptr, meta2, dinv2, b2, bufA);
    // readout
    mfma_gemm_k<HH, FF, true><<<GG, 256, 0, stream>>>(bufA, Wtr, br, out);
}

// Round 9
// 277.798 us; speedup vs baseline: 1.1830x; 1.0712x over previous
//
#include <hip/hip_runtime.h>
#include <hip/hip_bf16.h>
#include <math.h>

#define NN 100000
#define EE 600000
#define FF 64
#define HH 128
#define CHUNK 1024
#define NCHUNK ((NN + CHUNK - 1) / CHUNK)   // 98
#define NCHUNKS_M (NN / 16)                 // 6250 (exact)

typedef unsigned short u16;
typedef __attribute__((ext_vector_type(8))) short bf16x8;
typedef __attribute__((ext_vector_type(4))) float f32x4;

__device__ __forceinline__ u16 f2bf(float f) {
    __hip_bfloat16 h = __float2bfloat16(f);
    return *(u16*)&h;
}
__device__ __forceinline__ float bf2f(u16 u) {
    unsigned int t = ((unsigned int)u) << 16;
    return *(float*)&t;
}

// ---------------- CSR build ----------------

__global__ void count_k(const int* __restrict__ col, int* __restrict__ cnt) {
    int e = blockIdx.x * 256 + threadIdx.x;
    if (e < EE) atomicAdd(&cnt[col[e]], 1);
}

// chunk sums + dinv1 fused
__global__ void chunksum_k(const int* __restrict__ cnt, int* __restrict__ chunk_sum,
                           float* __restrict__ dinv1) {
    int b = blockIdx.x, t = threadIdx.x;
    int base = b * CHUNK + t * 4;
    int s = 0;
    #pragma unroll
    for (int i = 0; i < 4; i++) {
        int idx = base + i;
        if (idx < NN) {
            int cv = cnt[idx];
            s += cv;
            dinv1[idx] = rsqrtf((float)cv + 1.0f);
        }
    }
    __shared__ int sm[4];
    for (int d = 32; d > 0; d >>= 1) s += __shfl_down(s, d);
    if ((t & 63) == 0) sm[t >> 6] = s;
    __syncthreads();
    if (t == 0) chunk_sum[b] = sm[0] + sm[1] + sm[2] + sm[3];
}

__global__ void chunkoff_k(const int* __restrict__ chunk_sum, int* __restrict__ chunk_off,
                           int* __restrict__ col_ptr) {
    if (threadIdx.x == 0) {
        int run = 0;
        for (int i = 0; i < NCHUNK; i++) { chunk_off[i] = run; run += chunk_sum[i]; }
        col_ptr[NN] = run;   // == EE
    }
}

// col_ptr + cursor (cursor starts at col_ptr so fill needs one atomicAdd only)
__global__ void colptr_k(const int* __restrict__ cnt, const int* __restrict__ chunk_off,
                         int* __restrict__ col_ptr, int* __restrict__ cursor) {
    int b = blockIdx.x, t = threadIdx.x;
    int base = b * CHUNK + t * 4;
    int c[4]; int tot = 0;
    #pragma unroll
    for (int i = 0; i < 4; i++) { int idx = base + i; c[i] = (idx < NN) ? cnt[idx] : 0; tot += c[i]; }
    __shared__ int s[256];
    s[t] = tot;
    __syncthreads();
    for (int d = 1; d < 256; d <<= 1) {
        int v = (t >= d) ? s[t - d] : 0;
        __syncthreads();
        s[t] += v;
        __syncthreads();
    }
    int excl = s[t] - tot;
    int off = chunk_off[b] + excl;
    int pre = 0;
    #pragma unroll
    for (int i = 0; i < 4; i++) {
        int idx = base + i;
        if (idx < NN) {
            col_ptr[idx] = off + pre;
            cursor[idx] = off + pre;
        }
        pre += c[i];
    }
}

// fill CSR: single scatter target meta1 = (src, dinv1[r]*dinv1[c])
__global__ void fill_k(const int* __restrict__ row, const int* __restrict__ col,
                       int* __restrict__ cursor, const float* __restrict__ dinv1,
                       int2* __restrict__ meta1) {
    int e = blockIdx.x * 256 + threadIdx.x;
    if (e < EE) {
        int r = row[e], c = col[e];
        int slot = atomicAdd(&cursor[c], 1);
        float w = dinv1[r] * dinv1[c];
        meta1[slot] = make_int2(r, __float_as_int(w));
    }
}

// ---------------- fused prep: weight transpose+cast, gemv, x cast ----------------

__global__ void prep_k(const float* __restrict__ W0, const float* __restrict__ W1,
                       const float* __restrict__ W2, const float* __restrict__ Wr,
                       const float* __restrict__ Wg, const float* __restrict__ att_src,
                       const float* __restrict__ att_dst, const float* __restrict__ x,
                       u16* __restrict__ Wt0, u16* __restrict__ Wt1,
                       u16* __restrict__ Wt2, u16* __restrict__ Wtr,
                       float* __restrict__ vs, float* __restrict__ vd,
                       u16* __restrict__ xb) {
    int i = blockIdx.x * 256 + threadIdx.x;
    if (i < NN * FF / 4) {          // cast x -> bf16 (float4 granular)
        float4 v = ((const float4*)x)[i];
        ushort4 o;
        o.x = f2bf(v.x); o.y = f2bf(v.y); o.z = f2bf(v.z); o.w = f2bf(v.w);
        ((ushort4*)xb)[i] = o;
        return;
    }
    i -= NN * FF / 4;
    if (i < 8192) {                 // Wt0: [128][64] from W0[64][128]
        int n = i >> 6, k = i & 63;
        Wt0[i] = f2bf(W0[k * 128 + n]);
        return;
    }
    i -= 8192;
    if (i < 16384) {                // Wt1: [128][128]
        int n = i >> 7, k = i & 127;
        Wt1[i] = f2bf(W1[k * 128 + n]);
        return;
    }
    i -= 16384;
    if (i < 16384) {                // Wt2: [128][128]
        int n = i >> 7, k = i & 127;
        Wt2[i] = f2bf(W2[k * 128 + n]);
        return;
    }
    i -= 16384;
    if (i < 8192) {                 // Wtr: [64][128] from Wr[128][64]
        int n = i >> 7, k = i & 127;
        Wtr[i] = f2bf(Wr[k * 64 + n]);
        return;
    }
    i -= 8192;
    if (i < HH) {                   // gemv: vs/vd = Wg @ att_{src,dst}
        float s1 = 0.f, s2 = 0.f;
        for (int j = 0; j < HH; j++) {
            float w = Wg[i * HH + j];
            s1 += w * att_src[j];
            s2 += w * att_dst[j];
        }
        vs[i] = s1;
        vd[i] = s2;
    }
}

// ---------------- layer-1 aggregate in x-space: 8 groups x 8 lanes, 16B/lane ----------------

__global__ __launch_bounds__(256) void aggx_k(
    const u16* __restrict__ xb, const int* __restrict__ col_ptr, const int2* __restrict__ meta1,
    const float* __restrict__ dinv1, u16* __restrict__ xout) {
    int wid = threadIdx.x >> 6, lane = threadIdx.x & 63;
    int c = blockIdx.x * 4 + wid;
    if (c >= NN) return;
    int g = lane >> 3;           // group 0..7, one edge stream each
    int ch = (lane & 7) << 3;    // channel base 0,8,...,56
    int beg = col_ptr[c], end = col_ptr[c + 1];
    float acc[8] = {};

    int p = beg + g;
    int r = 0; float w = 0.f;
    if (p < end) { int2 m = meta1[p]; r = m.x; w = __int_as_float(m.y); }
    while (p < end) {
        bf16x8 v = *(const bf16x8*)&xb[(size_t)r * FF + ch];
        int p2 = p + 8;
        int r2 = 0; float w2 = 0.f;
        if (p2 < end) { int2 m = meta1[p2]; r2 = m.x; w2 = __int_as_float(m.y); }
        #pragma unroll
        for (int j = 0; j < 8; j++) acc[j] = fmaf(bf2f((u16)v[j]), w, acc[j]);
        p = p2; r = r2; w = w2;
    }
    // combine 8 groups (xor 8, 16, 32)
    #pragma unroll
    for (int j = 0; j < 8; j++) {
        acc[j] += __shfl_xor(acc[j], 8);
        acc[j] += __shfl_xor(acc[j], 16);
        acc[j] += __shfl_xor(acc[j], 32);
    }

    if (g == 0) {
        bf16x8 v = *(const bf16x8*)&xb[(size_t)c * FF + ch];
        float dc = dinv1[c];
        float ws = dc * dc;
        bf16x8 o;
        #pragma unroll
        for (int j = 0; j < 8; j++) {
            float t = fmaf(bf2f((u16)v[j]), ws, acc[j]);
            o[j] = (short)f2bf(t);
        }
        *(bf16x8*)&xout[(size_t)c * FF + ch] = o;
    }
}

// ---------------- GEMM1: x1 = relu(xagg @ W0 + b0), fused a_s/a_d ----------------

__global__ __launch_bounds__(256) void gemm1_k(const u16* __restrict__ A, const u16* __restrict__ Wt,
                                               const float* __restrict__ bias,
                                               const float* __restrict__ vs, const float* __restrict__ vd,
                                               u16* __restrict__ C, float* __restrict__ a_s,
                                               float* __restrict__ a_d) {
    constexpr int K = FF, N = HH, KK = K / 32, NT = N / 16;
    int lane = threadIdx.x & 63;
    int l15 = lane & 15, l4 = lane >> 4;
    int wg = blockIdx.x * 4 + (threadIdx.x >> 6);
    int nwaves = gridDim.x * 4;

    bf16x8 a_frag[KK][NT];
    #pragma unroll
    for (int kk = 0; kk < KK; kk++)
        #pragma unroll
        for (int nt = 0; nt < NT; nt++)
            a_frag[kk][nt] = *(const bf16x8*)&Wt[(size_t)(nt * 16 + l15) * K + kk * 32 + l4 * 8];
    f32x4 bias_f[NT], vs_f[NT], vd_f[NT];
    #pragma unroll
    for (int nt = 0; nt < NT; nt++) {
        bias_f[nt] = *(const f32x4*)&bias[nt * 16 + l4 * 4];
        vs_f[nt] = *(const f32x4*)&vs[nt * 16 + l4 * 4];
        vd_f[nt] = *(const f32x4*)&vd[nt * 16 + l4 * 4];
    }

    for (int ch = wg; ch < NCHUNKS_M; ch += nwaves) {
        int row = ch * 16 + l15;
        bf16x8 b_frag[KK];
        #pragma unroll
        for (int kk = 0; kk < KK; kk++)
            b_frag[kk] = *(const bf16x8*)&A[(size_t)row * K + kk * 32 + l4 * 8];
        f32x4 acc[NT] = {};
        #pragma unroll
        for (int kk = 0; kk < KK; kk++)
            #pragma unroll
            for (int nt = 0; nt < NT; nt++)
                acc[nt] = __builtin_amdgcn_mfma_f32_16x16x32_bf16(a_frag[kk][nt], b_frag[kk],
                                                                  acc[nt], 0, 0, 0);
        float s1 = 0.f, s2 = 0.f;
        #pragma unroll
        for (int nt = 0; nt < NT; nt++) {
            float o0 = fmaxf(acc[nt][0] + bias_f[nt][0], 0.f);
            float o1 = fmaxf(acc[nt][1] + bias_f[nt][1], 0.f);
            float o2 = fmaxf(acc[nt][2] + bias_f[nt][2], 0.f);
            float o3 = fmaxf(acc[nt][3] + bias_f[nt][3], 0.f);
            ushort4 o;
            o.x = f2bf(o0); o.y = f2bf(o1); o.z = f2bf(o2); o.w = f2bf(o3);
            *(ushort4*)&C[(size_t)row * N + nt * 16 + l4 * 4] = o;
            s1 += o0 * vs_f[nt][0] + o1 * vs_f[nt][1] + o2 * vs_f[nt][2] + o3 * vs_f[nt][3];
            s2 += o0 * vd_f[nt][0] + o1 * vd_f[nt][1] + o2 * vd_f[nt][2] + o3 * vd_f[nt][3];
        }
        s1 += __shfl_xor(s1, 16); s1 += __shfl_xor(s1, 32);
        s2 += __shfl_xor(s2, 16); s2 += __shfl_xor(s2, 32);
        if (l4 == 0) {
            a_s[row] = s1;
            a_d[row] = s2;
        }
    }
}

// ---------------- MFMA GEMM (layers 2/3 + readout) ----------------

template <int K, int N, bool OUTF32>
__global__ __launch_bounds__(256) void mfma_gemm_k(const u16* __restrict__ A,
                                                   const u16* __restrict__ Wt,
                                                   const float* __restrict__ bias,
                                                   void* __restrict__ C_) {
    constexpr int KK = K / 32;
    constexpr int NT = N / 16;
    int lane = threadIdx.x & 63;
    int l15 = lane & 15, l4 = lane >> 4;
    int wg = blockIdx.x * 4 + (threadIdx.x >> 6);
    int nwaves = gridDim.x * 4;

    bf16x8 a_frag[KK][NT];
    #pragma unroll
    for (int kk = 0; kk < KK; kk++)
        #pragma unroll
        for (int nt = 0; nt < NT; nt++)
            a_frag[kk][nt] = *(const bf16x8*)&Wt[(size_t)(nt * 16 + l15) * K + kk * 32 + l4 * 8];

    f32x4 bias_f[NT];
    if (OUTF32) {
        #pragma unroll
        for (int nt = 0; nt < NT; nt++)
            bias_f[nt] = *(const f32x4*)&bias[nt * 16 + l4 * 4];
    }

    float* Cf = (float*)C_;
    u16* Cb = (u16*)C_;

    for (int ch = wg; ch < NCHUNKS_M; ch += nwaves) {
        int row = ch * 16 + l15;
        bf16x8 b_frag[KK];
        #pragma unroll
        for (int kk = 0; kk < KK; kk++)
            b_frag[kk] = *(const bf16x8*)&A[(size_t)row * K + kk * 32 + l4 * 8];
        f32x4 acc[NT] = {};
        #pragma unroll
        for (int kk = 0; kk < KK; kk++)
            #pragma unroll
            for (int nt = 0; nt < NT; nt++)
                acc[nt] = __builtin_amdgcn_mfma_f32_16x16x32_bf16(a_frag[kk][nt], b_frag[kk],
                                                                  acc[nt], 0, 0, 0);
        #pragma unroll
        for (int nt = 0; nt < NT; nt++) {
            int col = nt * 16 + l4 * 4;
            if (OUTF32) {
                float4 o;
                o.x = acc[nt][0] + bias_f[nt][0];
                o.y = acc[nt][1] + bias_f[nt][1];
                o.z = acc[nt][2] + bias_f[nt][2];
                o.w = acc[nt][3] + bias_f[nt][3];
                *(float4*)&Cf[(size_t)row * N + col] = o;
            } else {
                ushort4 o;
                o.x = f2bf(acc[nt][0]);
                o.y = f2bf(acc[nt][1]);
                o.z = f2bf(acc[nt][2]);
                o.w = f2bf(acc[nt][3]);
                *(ushort4*)&Cb[(size_t)row * N + col] = o;
            }
        }
    }
}

// ---------------- attention: 8 lanes per node, online softmax ----------------
// writes alpha[p] = softmax * dinv2[c]  (dinv2[r] applied by w2_k)

__global__ __launch_bounds__(256) void attn_k(const int* __restrict__ col_ptr,
                                              const int2* __restrict__ meta1,
                                              const float* __restrict__ a_s,
                                              const float* __restrict__ a_d,
                                              float* __restrict__ alpha,
                                              float* __restrict__ dinv2) {
    int lane = threadIdx.x & 63, wid = threadIdx.x >> 6;
    int grp = lane >> 3, idx = lane & 7;
    int c = blockIdx.x * 32 + wid * 8 + grp;
    if (c >= NN) return;
    int beg = col_ptr[c], end = col_ptr[c + 1];
    float ad = a_d[c];
    float es = a_s[c] + ad;
    es = (es > 0.f) ? es : 0.2f * es;
    float m = (idx == 0) ? es : -1e30f;
    float s = (idx == 0) ? 1.f : 0.f;
    for (int p = beg + idx; p < end; p += 8) {
        float e = a_s[meta1[p].x] + ad;
        e = (e > 0.f) ? e : 0.2f * e;
        alpha[p] = e;
        float mn = fmaxf(m, e);
        s = s * expf(m - mn) + expf(e - mn);
        m = mn;
    }
    #pragma unroll
    for (int d = 1; d < 8; d <<= 1) {
        float mo = __shfl_xor(m, d);
        float so = __shfl_xor(s, d);
        float mn = fmaxf(m, mo);
        s = s * expf(m - mn) + so * expf(mo - mn);
        m = mn;
    }
    float inv = 1.f / s;
    float aself = expf(es - m) * inv;
    float d2 = rsqrtf(2.f - aself);
    if (idx == 0) dinv2[c] = d2;
    float sc = inv * d2;
    for (int p = beg + idx; p < end; p += 8)
        alpha[p] = expf(alpha[p] - m) * sc;
}

// meta2[p] = (src, alpha[p] * dinv2[src])  — completes w = dinv2[r]*alpha*dinv2[c]
__global__ void w2_k(const int2* __restrict__ meta1, const float* __restrict__ dinv2,
                     const float* __restrict__ alpha, int2* __restrict__ meta2) {
    int p = blockIdx.x * 256 + threadIdx.x;
    if (p < EE) {
        int r = meta1[p].x;
        float w = alpha[p] * dinv2[r];
        meta2[p] = make_int2(r, __float_as_int(w));
    }
}

// ---------------- layers 2/3 aggregate: 4 groups x 16 lanes x 2 streams, 16B/lane ----------------

__global__ __launch_bounds__(256) void agg2_k(
    const u16* __restrict__ xw, const int* __restrict__ col_ptr, const int2* __restrict__ meta2,
    const float* __restrict__ dinv2, const float* __restrict__ bias, u16* __restrict__ xout) {
    int wid = threadIdx.x >> 6, lane = threadIdx.x & 63;
    int c = blockIdx.x * 4 + wid;
    if (c >= NN) return;
    int g = lane >> 4;            // group 0..3
    int ch = (lane & 15) << 3;    // channel base 0,8,...,120
    int beg = col_ptr[c], end = col_ptr[c + 1];
    float acc[8] = {};

    int pA = beg + g, pB = pA + 4;
    int rA = 0, rB = 0; float wA = 0.f, wB = 0.f;
    if (pA < end) { int2 m = meta2[pA]; rA = m.x; wA = __int_as_float(m.y); }
    if (pB < end) { int2 m = meta2[pB]; rB = m.x; wB = __int_as_float(m.y); }
    while (pA < end) {
        bool hb = pB < end;
        bf16x8 vA = *(const bf16x8*)&xw[(size_t)rA * HH + ch];
        bf16x8 vB;
        if (hb) vB = *(const bf16x8*)&xw[(size_t)rB * HH + ch];
        int pA2 = pA + 8, pB2 = pB + 8;
        int rA2 = 0, rB2 = 0; float wA2 = 0.f, wB2 = 0.f;
        if (pA2 < end) { int2 m = meta2[pA2]; rA2 = m.x; wA2 = __int_as_float(m.y); }
        if (pB2 < end) { int2 m = meta2[pB2]; rB2 = m.x; wB2 = __int_as_float(m.y); }
        #pragma unroll
        for (int j = 0; j < 8; j++) acc[j] = fmaf(bf2f((u16)vA[j]), wA, acc[j]);
        if (hb) {
            #pragma unroll
            for (int j = 0; j < 8; j++) acc[j] = fmaf(bf2f((u16)vB[j]), wB, acc[j]);
        }
        pA = pA2; pB = pB2; rA = rA2; rB = rB2; wA = wA2; wB = wB2;
    }
    // combine 4 groups (xor 16, 32)
    #pragma unroll
    for (int j = 0; j < 8; j++) {
        acc[j] += __shfl_xor(acc[j], 16);
        acc[j] += __shfl_xor(acc[j], 32);
    }

    if (g == 0) {
        bf16x8 v = *(const bf16x8*)&xw[(size_t)c * HH + ch];
        float dc = dinv2[c];
        float ws = dc * dc;
        f32x4 b4a = *(const f32x4*)&bias[ch];
        f32x4 b4b = *(const f32x4*)&bias[ch + 4];
        bf16x8 o;
        #pragma unroll
        for (int j = 0; j < 8; j++) {
            float bj = (j < 4) ? b4a[j] : b4b[j - 4];
            float t = fmaxf(fmaf(bf2f((u16)v[j]), ws, acc[j]) + bj, 0.f);
            o[j] = (short)f2bf(t);
        }
        *(bf16x8*)&xout[(size_t)c * HH + ch] = o;
    }
}

// ---------------- launch ----------------

extern "C" void kernel_launch(void* const* d_in, const int* in_sizes, int n_in,
                              void* d_out, int out_size, void* d_ws, size_t ws_size,
                              hipStream_t stream) {
    const float* x = (const float*)d_in[0];
    const int* eidx = (const int*)d_in[1];     // [2][E]: row, col
    const float* W0 = (const float*)d_in[3];
    const float* b0 = (const float*)d_in[4];
    const float* Wg = (const float*)d_in[5];
    const float* att_src = (const float*)d_in[6];
    const float* att_dst = (const float*)d_in[7];
    const float* W1 = (const float*)d_in[8];
    const float* b1 = (const float*)d_in[9];
    const float* W2 = (const float*)d_in[10];
    const float* b2 = (const float*)d_in[11];
    const float* Wr = (const float*)d_in[12];
    const float* br = (const float*)d_in[13];
    float* out = (float*)d_out;

    const int* erow = eidx;
    const int* ecol = eidx + EE;

    char* p = (char*)d_ws;
    auto alloc = [&](size_t bytes) {
        void* r = (void*)p;
        p += (bytes + 255) & ~(size_t)255;
        return r;
    };
    int* col_ptr = (int*)alloc((NN + 1) * sizeof(int));
    int2* meta1 = (int2*)alloc(EE * sizeof(int2));
    int2* meta2 = (int2*)alloc(EE * sizeof(int2));
    int* cnt = (int*)alloc(NN * sizeof(int));
    int* cursor = (int*)alloc(NN * sizeof(int));
    int* chunk_sum = (int*)alloc(128 * sizeof(int));
    int* chunk_off = (int*)alloc(128 * sizeof(int));
    float* alpha = (float*)alloc(EE * sizeof(float));
    float* dinv1 = (float*)alloc(NN * sizeof(float));
    float* dinv2 = (float*)alloc(NN * sizeof(float));
    float* a_s = (float*)alloc(NN * sizeof(float));
    float* a_d = (float*)alloc(NN * sizeof(float));
    float* vs = (float*)alloc(HH * sizeof(float));
    float* vd = (float*)alloc(HH * sizeof(float));
    u16* Wt0 = (u16*)alloc(8192 * sizeof(u16));    // [128][64]
    u16* Wt1 = (u16*)alloc(16384 * sizeof(u16));   // [128][128]
    u16* Wt2 = (u16*)alloc(16384 * sizeof(u16));   // [128][128]
    u16* Wtr = (u16*)alloc(8192 * sizeof(u16));    // [64][128]
    u16* xb = (u16*)alloc((size_t)NN * FF * sizeof(u16));     // bf16(x)
    u16* xaggb = (u16*)alloc((size_t)NN * FF * sizeof(u16));  // bf16(Â x)
    u16* bufA = (u16*)alloc((size_t)NN * HH * sizeof(u16));
    u16* bufB = (u16*)alloc((size_t)NN * HH * sizeof(u16));

    hipMemsetAsync(cnt, 0, NN * sizeof(int), stream);

    count_k<<<(EE + 255) / 256, 256, 0, stream>>>(ecol, cnt);
    chunksum_k<<<NCHUNK, 256, 0, stream>>>(cnt, chunk_sum, dinv1);
    chunkoff_k<<<1, 64, 0, stream>>>(chunk_sum, chunk_off, col_ptr);
    colptr_k<<<NCHUNK, 256, 0, stream>>>(cnt, chunk_off, col_ptr, cursor);
    fill_k<<<(EE + 255) / 256, 256, 0, stream>>>(erow, ecol, cursor, dinv1, meta1);
    // prep: x cast + weight transpose/cast + gemv
    prep_k<<<(NN * FF / 4 + 49280 + 255) / 256, 256, 0, stream>>>(
        W0, W1, W2, Wr, Wg, att_src, att_dst, x, Wt0, Wt1, Wt2, Wtr, vs, vd, xb);

    int aggGrid = (NN + 3) / 4;
    const int GG = 512;

    // layer 1: xagg = Â1 x ; x1 = relu(xagg@W0+b0) + fused a_s/a_d
    aggx_k<<<aggGrid, 256, 0, stream>>>(xb, col_ptr, meta1, dinv1, xaggb);
    gemm1_k<<<GG, 256, 0, stream>>>(xaggb, Wt0, b0, vs, vd, bufA, a_s, a_d);
    // attention
    attn_k<<<(NN + 31) / 32, 256, 0, stream>>>(col_ptr, meta1, a_s, a_d, alpha, dinv2);
    w2_k<<<(EE + 255) / 256, 256, 0, stream>>>(meta1, dinv2, alpha, meta2);
    // layer 2
    mfma_gemm_k<HH, HH, false><<<GG, 256, 0, stream>>>(bufA, Wt1, nullptr, bufB);
    agg2_k<<<aggGrid, 256, 0, stream>>>(bufB, col_ptr, meta2, dinv2, b1, bufA);
    // layer 3
    mfma_gemm_k<HH, HH, false><<<GG, 256, 0, stream>>>(bufA, Wt2, nullptr, bufB);
    agg2_k<<<aggGrid, 256, 0, stream>>>(bufB, col_ptr, meta2, dinv2, b2, bufA);
    // readout
    mfma_gemm_k<HH, FF, true><<<GG, 256, 0, stream>>>(bufA, Wtr, br, out);
}

// Round 10
// 247.842 us; speedup vs baseline: 1.3260x; 1.1209x over previous
//
#include <hip/hip_runtime.h>
#include <hip/hip_bf16.h>
#include <hip/hip_fp16.h>
#include <math.h>

#define NN 100000
#define EE 600000
#define FF 64
#define HH 128
#define CHUNK 1024
#define NCHUNK ((NN + CHUNK - 1) / CHUNK)   // 98
#define NCHUNKS_M (NN / 16)                 // 6250 (exact)
#define PREP_ITEMS (NN * FF / 4 + 49280)

typedef unsigned short u16;
typedef unsigned int u32;
typedef __attribute__((ext_vector_type(8))) short bf16x8;
typedef __attribute__((ext_vector_type(4))) float f32x4;

__device__ __forceinline__ u16 f2bf(float f) {
    __hip_bfloat16 h = __float2bfloat16(f);
    return *(u16*)&h;
}
__device__ __forceinline__ float bf2f(u16 u) {
    unsigned int t = ((unsigned int)u) << 16;
    return *(float*)&t;
}
// meta pack: src in bits [31:15], fp16 weight (sign dropped, w>0) in [14:0]
__device__ __forceinline__ u32 enc_meta(int r, float w) {
    u16 hb = __half_as_ushort(__float2half(w));
    return ((u32)r << 15) | (hb & 0x7fffu);
}
__device__ __forceinline__ void dec_meta(u32 u, int& r, float& w) {
    r = (int)(u >> 15);
    w = __half2float(__ushort_as_half((u16)(u & 0x7fffu)));
}

// ---------------- fused: edge count (atomics) + weight/x prep ----------------

__global__ void build_k(const int* __restrict__ col, int* __restrict__ cnt,
                        const float* __restrict__ W0, const float* __restrict__ W1,
                        const float* __restrict__ W2, const float* __restrict__ Wr,
                        const float* __restrict__ Wg, const float* __restrict__ att_src,
                        const float* __restrict__ att_dst, const float* __restrict__ x,
                        u16* __restrict__ Wt0, u16* __restrict__ Wt1,
                        u16* __restrict__ Wt2, u16* __restrict__ Wtr,
                        float* __restrict__ vs, float* __restrict__ vd,
                        u16* __restrict__ xb) {
    int i = blockIdx.x * 256 + threadIdx.x;
    if (i < EE) {
        atomicAdd(&cnt[col[i]], 1);
        return;
    }
    i -= EE;
    if (i < NN * FF / 4) {          // cast x -> bf16
        float4 v = ((const float4*)x)[i];
        ushort4 o;
        o.x = f2bf(v.x); o.y = f2bf(v.y); o.z = f2bf(v.z); o.w = f2bf(v.w);
        ((ushort4*)xb)[i] = o;
        return;
    }
    i -= NN * FF / 4;
    if (i < 8192) {                 // Wt0: [128][64] from W0[64][128]
        int n = i >> 6, k = i & 63;
        Wt0[i] = f2bf(W0[k * 128 + n]);
        return;
    }
    i -= 8192;
    if (i < 16384) {                // Wt1: [128][128]
        int n = i >> 7, k = i & 127;
        Wt1[i] = f2bf(W1[k * 128 + n]);
        return;
    }
    i -= 16384;
    if (i < 16384) {                // Wt2: [128][128]
        int n = i >> 7, k = i & 127;
        Wt2[i] = f2bf(W2[k * 128 + n]);
        return;
    }
    i -= 16384;
    if (i < 8192) {                 // Wtr: [64][128] from Wr[128][64]
        int n = i >> 7, k = i & 127;
        Wtr[i] = f2bf(Wr[k * 64 + n]);
        return;
    }
    i -= 8192;
    if (i < HH) {                   // gemv: vs/vd = Wg @ att_{src,dst}
        float s1 = 0.f, s2 = 0.f;
        for (int j = 0; j < HH; j++) {
            float w = Wg[i * HH + j];
            s1 += w * att_src[j];
            s2 += w * att_dst[j];
        }
        vs[i] = s1;
        vd[i] = s2;
    }
}

// chunk sums + dinv1 fused
__global__ void chunksum_k(const int* __restrict__ cnt, int* __restrict__ chunk_sum,
                           float* __restrict__ dinv1) {
    int b = blockIdx.x, t = threadIdx.x;
    int base = b * CHUNK + t * 4;
    int s = 0;
    #pragma unroll
    for (int i = 0; i < 4; i++) {
        int idx = base + i;
        if (idx < NN) {
            int cv = cnt[idx];
            s += cv;
            dinv1[idx] = rsqrtf((float)cv + 1.0f);
        }
    }
    __shared__ int sm[4];
    for (int d = 32; d > 0; d >>= 1) s += __shfl_down(s, d);
    if ((t & 63) == 0) sm[t >> 6] = s;
    __syncthreads();
    if (t == 0) chunk_sum[b] = sm[0] + sm[1] + sm[2] + sm[3];
}

__global__ void chunkoff_k(const int* __restrict__ chunk_sum, int* __restrict__ chunk_off,
                           int* __restrict__ col_ptr) {
    if (threadIdx.x == 0) {
        int run = 0;
        for (int i = 0; i < NCHUNK; i++) { chunk_off[i] = run; run += chunk_sum[i]; }
        col_ptr[NN] = run;   // == EE
    }
}

__global__ void colptr_k(const int* __restrict__ cnt, const int* __restrict__ chunk_off,
                         int* __restrict__ col_ptr, int* __restrict__ cursor) {
    int b = blockIdx.x, t = threadIdx.x;
    int base = b * CHUNK + t * 4;
    int c[4]; int tot = 0;
    #pragma unroll
    for (int i = 0; i < 4; i++) { int idx = base + i; c[i] = (idx < NN) ? cnt[idx] : 0; tot += c[i]; }
    __shared__ int s[256];
    s[t] = tot;
    __syncthreads();
    for (int d = 1; d < 256; d <<= 1) {
        int v = (t >= d) ? s[t - d] : 0;
        __syncthreads();
        s[t] += v;
        __syncthreads();
    }
    int excl = s[t] - tot;
    int off = chunk_off[b] + excl;
    int pre = 0;
    #pragma unroll
    for (int i = 0; i < 4; i++) {
        int idx = base + i;
        if (idx < NN) {
            col_ptr[idx] = off + pre;
            cursor[idx] = off + pre;
        }
        pre += c[i];
    }
}

// fill CSR: single 4B scatter meta1 = enc(src, dinv1[r]*dinv1[c])
__global__ void fill_k(const int* __restrict__ row, const int* __restrict__ col,
                       int* __restrict__ cursor, const float* __restrict__ dinv1,
                       u32* __restrict__ meta1) {
    int e = blockIdx.x * 256 + threadIdx.x;
    if (e < EE) {
        int r = row[e], c = col[e];
        int slot = atomicAdd(&cursor[c], 1);
        meta1[slot] = enc_meta(r, dinv1[r] * dinv1[c]);
    }
}

// ---------------- layer-1 aggregate: 2 nodes/wave, 4 groups x 8 lanes, 16B/lane ----------------

__global__ __launch_bounds__(256) void aggx_k(
    const u16* __restrict__ xb, const int* __restrict__ col_ptr, const u32* __restrict__ meta1,
    const float* __restrict__ dinv1, u16* __restrict__ xout) {
    int wid = threadIdx.x >> 6, lane = threadIdx.x & 63;
    int sub = lane >> 5;
    int c = blockIdx.x * 8 + wid * 2 + sub;
    int hl = lane & 31;
    int g = hl >> 3;             // group 0..3
    int ch = (hl & 7) << 3;      // channel base 0,8,...,56
    int beg = col_ptr[c], end = col_ptr[c + 1];
    float acc[8] = {};

    int p = beg + g;
    int r = 0; float w = 0.f;
    if (p < end) dec_meta(meta1[p], r, w);
    while (p < end) {
        bf16x8 v = *(const bf16x8*)&xb[(size_t)r * FF + ch];
        int p2 = p + 4;
        int r2 = 0; float w2 = 0.f;
        if (p2 < end) dec_meta(meta1[p2], r2, w2);
        #pragma unroll
        for (int j = 0; j < 8; j++) acc[j] = fmaf(bf2f((u16)v[j]), w, acc[j]);
        p = p2; r = r2; w = w2;
    }
    // combine 4 groups within half-wave (xor 8, 16)
    #pragma unroll
    for (int j = 0; j < 8; j++) {
        acc[j] += __shfl_xor(acc[j], 8);
        acc[j] += __shfl_xor(acc[j], 16);
    }

    if (g == 0) {
        bf16x8 v = *(const bf16x8*)&xb[(size_t)c * FF + ch];
        float dc = dinv1[c];
        float ws = dc * dc;
        bf16x8 o;
        #pragma unroll
        for (int j = 0; j < 8; j++) {
            float t = fmaf(bf2f((u16)v[j]), ws, acc[j]);
            o[j] = (short)f2bf(t);
        }
        *(bf16x8*)&xout[(size_t)c * FF + ch] = o;
    }
}

// ---------------- GEMM1: x1 = relu(xagg @ W0 + b0), fused a_s/a_d ----------------

__global__ __launch_bounds__(256) void gemm1_k(const u16* __restrict__ A, const u16* __restrict__ Wt,
                                               const float* __restrict__ bias,
                                               const float* __restrict__ vs, const float* __restrict__ vd,
                                               u16* __restrict__ C, float* __restrict__ a_s,
                                               float* __restrict__ a_d) {
    constexpr int K = FF, N = HH, KK = K / 32, NT = N / 16;
    int lane = threadIdx.x & 63;
    int l15 = lane & 15, l4 = lane >> 4;
    int wg = blockIdx.x * 4 + (threadIdx.x >> 6);
    int nwaves = gridDim.x * 4;

    bf16x8 a_frag[KK][NT];
    #pragma unroll
    for (int kk = 0; kk < KK; kk++)
        #pragma unroll
        for (int nt = 0; nt < NT; nt++)
            a_frag[kk][nt] = *(const bf16x8*)&Wt[(size_t)(nt * 16 + l15) * K + kk * 32 + l4 * 8];
    f32x4 bias_f[NT], vs_f[NT], vd_f[NT];
    #pragma unroll
    for (int nt = 0; nt < NT; nt++) {
        bias_f[nt] = *(const f32x4*)&bias[nt * 16 + l4 * 4];
        vs_f[nt] = *(const f32x4*)&vs[nt * 16 + l4 * 4];
        vd_f[nt] = *(const f32x4*)&vd[nt * 16 + l4 * 4];
    }

    for (int ch = wg; ch < NCHUNKS_M; ch += nwaves) {
        int row = ch * 16 + l15;
        bf16x8 b_frag[KK];
        #pragma unroll
        for (int kk = 0; kk < KK; kk++)
            b_frag[kk] = *(const bf16x8*)&A[(size_t)row * K + kk * 32 + l4 * 8];
        f32x4 acc[NT] = {};
        #pragma unroll
        for (int kk = 0; kk < KK; kk++)
            #pragma unroll
            for (int nt = 0; nt < NT; nt++)
                acc[nt] = __builtin_amdgcn_mfma_f32_16x16x32_bf16(a_frag[kk][nt], b_frag[kk],
                                                                  acc[nt], 0, 0, 0);
        float s1 = 0.f, s2 = 0.f;
        #pragma unroll
        for (int nt = 0; nt < NT; nt++) {
            float o0 = fmaxf(acc[nt][0] + bias_f[nt][0], 0.f);
            float o1 = fmaxf(acc[nt][1] + bias_f[nt][1], 0.f);
            float o2 = fmaxf(acc[nt][2] + bias_f[nt][2], 0.f);
            float o3 = fmaxf(acc[nt][3] + bias_f[nt][3], 0.f);
            ushort4 o;
            o.x = f2bf(o0); o.y = f2bf(o1); o.z = f2bf(o2); o.w = f2bf(o3);
            *(ushort4*)&C[(size_t)row * N + nt * 16 + l4 * 4] = o;
            s1 += o0 * vs_f[nt][0] + o1 * vs_f[nt][1] + o2 * vs_f[nt][2] + o3 * vs_f[nt][3];
            s2 += o0 * vd_f[nt][0] + o1 * vd_f[nt][1] + o2 * vd_f[nt][2] + o3 * vd_f[nt][3];
        }
        s1 += __shfl_xor(s1, 16); s1 += __shfl_xor(s1, 32);
        s2 += __shfl_xor(s2, 16); s2 += __shfl_xor(s2, 32);
        if (l4 == 0) {
            a_s[row] = s1;
            a_d[row] = s2;
        }
    }
}

// ---------------- MFMA GEMM (layers 2/3 + readout) ----------------

template <int K, int N, bool OUTF32>
__global__ __launch_bounds__(256) void mfma_gemm_k(const u16* __restrict__ A,
                                                   const u16* __restrict__ Wt,
                                                   const float* __restrict__ bias,
                                                   void* __restrict__ C_) {
    constexpr int KK = K / 32;
    constexpr int NT = N / 16;
    int lane = threadIdx.x & 63;
    int l15 = lane & 15, l4 = lane >> 4;
    int wg = blockIdx.x * 4 + (threadIdx.x >> 6);
    int nwaves = gridDim.x * 4;

    bf16x8 a_frag[KK][NT];
    #pragma unroll
    for (int kk = 0; kk < KK; kk++)
        #pragma unroll
        for (int nt = 0; nt < NT; nt++)
            a_frag[kk][nt] = *(const bf16x8*)&Wt[(size_t)(nt * 16 + l15) * K + kk * 32 + l4 * 8];

    f32x4 bias_f[NT];
    if (OUTF32) {
        #pragma unroll
        for (int nt = 0; nt < NT; nt++)
            bias_f[nt] = *(const f32x4*)&bias[nt * 16 + l4 * 4];
    }

    float* Cf = (float*)C_;
    u16* Cb = (u16*)C_;

    for (int ch = wg; ch < NCHUNKS_M; ch += nwaves) {
        int row = ch * 16 + l15;
        bf16x8 b_frag[KK];
        #pragma unroll
        for (int kk = 0; kk < KK; kk++)
            b_frag[kk] = *(const bf16x8*)&A[(size_t)row * K + kk * 32 + l4 * 8];
        f32x4 acc[NT] = {};
        #pragma unroll
        for (int kk = 0; kk < KK; kk++)
            #pragma unroll
            for (int nt = 0; nt < NT; nt++)
                acc[nt] = __builtin_amdgcn_mfma_f32_16x16x32_bf16(a_frag[kk][nt], b_frag[kk],
                                                                  acc[nt], 0, 0, 0);
        #pragma unroll
        for (int nt = 0; nt < NT; nt++) {
            int col = nt * 16 + l4 * 4;
            if (OUTF32) {
                float4 o;
                o.x = acc[nt][0] + bias_f[nt][0];
                o.y = acc[nt][1] + bias_f[nt][1];
                o.z = acc[nt][2] + bias_f[nt][2];
                o.w = acc[nt][3] + bias_f[nt][3];
                *(float4*)&Cf[(size_t)row * N + col] = o;
            } else {
                ushort4 o;
                o.x = f2bf(acc[nt][0]);
                o.y = f2bf(acc[nt][1]);
                o.z = f2bf(acc[nt][2]);
                o.w = f2bf(acc[nt][3]);
                *(ushort4*)&Cb[(size_t)row * N + col] = o;
            }
        }
    }
}

// ---------------- attention: 8 lanes per node, online softmax ----------------
// writes alpha[p] = softmax * dinv2[c]  (dinv2[r] applied by w2_k)

__global__ __launch_bounds__(256) void attn_k(const int* __restrict__ col_ptr,
                                              const u32* __restrict__ meta1,
                                              const float* __restrict__ a_s,
                                              const float* __restrict__ a_d,
                                              float* __restrict__ alpha,
                                              float* __restrict__ dinv2) {
    int lane = threadIdx.x & 63, wid = threadIdx.x >> 6;
    int grp = lane >> 3, idx = lane & 7;
    int c = blockIdx.x * 32 + wid * 8 + grp;
    if (c >= NN) return;
    int beg = col_ptr[c], end = col_ptr[c + 1];
    float ad = a_d[c];
    float es = a_s[c] + ad;
    es = (es > 0.f) ? es : 0.2f * es;
    float m = (idx == 0) ? es : -1e30f;
    float s = (idx == 0) ? 1.f : 0.f;
    for (int p = beg + idx; p < end; p += 8) {
        float e = a_s[meta1[p] >> 15] + ad;
        e = (e > 0.f) ? e : 0.2f * e;
        alpha[p] = e;
        float mn = fmaxf(m, e);
        s = s * expf(m - mn) + expf(e - mn);
        m = mn;
    }
    #pragma unroll
    for (int d = 1; d < 8; d <<= 1) {
        float mo = __shfl_xor(m, d);
        float so = __shfl_xor(s, d);
        float mn = fmaxf(m, mo);
        s = s * expf(m - mn) + so * expf(mo - mn);
        m = mn;
    }
    float inv = 1.f / s;
    float aself = expf(es - m) * inv;
    float d2 = rsqrtf(2.f - aself);
    if (idx == 0) dinv2[c] = d2;
    float sc = inv * d2;
    for (int p = beg + idx; p < end; p += 8)
        alpha[p] = expf(alpha[p] - m) * sc;
}

// meta2[p] = enc(src, alpha[p] * dinv2[src])
__global__ void w2_k(const u32* __restrict__ meta1, const float* __restrict__ dinv2,
                     const float* __restrict__ alpha, u32* __restrict__ meta2) {
    int p = blockIdx.x * 256 + threadIdx.x;
    if (p < EE) {
        u32 u = meta1[p];
        int r = (int)(u >> 15);
        float w = alpha[p] * dinv2[r];
        u16 hb = __half_as_ushort(__float2half(w));
        meta2[p] = (u & 0xffff8000u) | (hb & 0x7fffu);
    }
}

// ---------------- layers 2/3 aggregate: 2 nodes/wave, 2 groups x 16 lanes x 2 streams ----------------

__global__ __launch_bounds__(256) void agg2_k(
    const u16* __restrict__ xw, const int* __restrict__ col_ptr, const u32* __restrict__ meta2,
    const float* __restrict__ dinv2, const float* __restrict__ bias, u16* __restrict__ xout) {
    int wid = threadIdx.x >> 6, lane = threadIdx.x & 63;
    int sub = lane >> 5;
    int c = blockIdx.x * 8 + wid * 2 + sub;
    int hl = lane & 31;
    int g = hl >> 4;              // group 0..1
    int ch = (hl & 15) << 3;      // channel base 0,8,...,120
    int beg = col_ptr[c], end = col_ptr[c + 1];
    float acc[8] = {};

    int pA = beg + g, pB = pA + 2;
    int rA = 0, rB = 0; float wA = 0.f, wB = 0.f;
    if (pA < end) dec_meta(meta2[pA], rA, wA);
    if (pB < end) dec_meta(meta2[pB], rB, wB);
    while (pA < end) {
        bool hb = pB < end;
        bf16x8 vA = *(const bf16x8*)&xw[(size_t)rA * HH + ch];
        bf16x8 vB;
        if (hb) vB = *(const bf16x8*)&xw[(size_t)rB * HH + ch];
        int pA2 = pA + 4, pB2 = pB + 4;
        int rA2 = 0, rB2 = 0; float wA2 = 0.f, wB2 = 0.f;
        if (pA2 < end) dec_meta(meta2[pA2], rA2, wA2);
        if (pB2 < end) dec_meta(meta2[pB2], rB2, wB2);
        #pragma unroll
        for (int j = 0; j < 8; j++) acc[j] = fmaf(bf2f((u16)vA[j]), wA, acc[j]);
        if (hb) {
            #pragma unroll
            for (int j = 0; j < 8; j++) acc[j] = fmaf(bf2f((u16)vB[j]), wB, acc[j]);
        }
        pA = pA2; pB = pB2; rA = rA2; rB = rB2; wA = wA2; wB = wB2;
    }
    // combine 2 groups within half-wave (xor 16)
    #pragma unroll
    for (int j = 0; j < 8; j++) acc[j] += __shfl_xor(acc[j], 16);

    if (g == 0) {
        bf16x8 v = *(const bf16x8*)&xw[(size_t)c * HH + ch];
        float dc = dinv2[c];
        float ws = dc * dc;
        f32x4 b4a = *(const f32x4*)&bias[ch];
        f32x4 b4b = *(const f32x4*)&bias[ch + 4];
        bf16x8 o;
        #pragma unroll
        for (int j = 0; j < 8; j++) {
            float bj = (j < 4) ? b4a[j] : b4b[j - 4];
            float t = fmaxf(fmaf(bf2f((u16)v[j]), ws, acc[j]) + bj, 0.f);
            o[j] = (short)f2bf(t);
        }
        *(bf16x8*)&xout[(size_t)c * HH + ch] = o;
    }
}

// ---------------- launch ----------------

extern "C" void kernel_launch(void* const* d_in, const int* in_sizes, int n_in,
                              void* d_out, int out_size, void* d_ws, size_t ws_size,
                              hipStream_t stream) {
    const float* x = (const float*)d_in[0];
    const int* eidx = (const int*)d_in[1];     // [2][E]: row, col
    const float* W0 = (const float*)d_in[3];
    const float* b0 = (const float*)d_in[4];
    const float* Wg = (const float*)d_in[5];
    const float* att_src = (const float*)d_in[6];
    const float* att_dst = (const float*)d_in[7];
    const float* W1 = (const float*)d_in[8];
    const float* b1 = (const float*)d_in[9];
    const float* W2 = (const float*)d_in[10];
    const float* b2 = (const float*)d_in[11];
    const float* Wr = (const float*)d_in[12];
    const float* br = (const float*)d_in[13];
    float* out = (float*)d_out;

    const int* erow = eidx;
    const int* ecol = eidx + EE;

    char* p = (char*)d_ws;
    auto alloc = [&](size_t bytes) {
        void* r = (void*)p;
        p += (bytes + 255) & ~(size_t)255;
        return r;
    };
    int* col_ptr = (int*)alloc((NN + 1) * sizeof(int));
    u32* meta1 = (u32*)alloc(EE * sizeof(u32));
    u32* meta2 = (u32*)alloc(EE * sizeof(u32));
    int* cnt = (int*)alloc(NN * sizeof(int));
    int* cursor = (int*)alloc(NN * sizeof(int));
    int* chunk_sum = (int*)alloc(128 * sizeof(int));
    int* chunk_off = (int*)alloc(128 * sizeof(int));
    float* alpha = (float*)alloc(EE * sizeof(float));
    float* dinv1 = (float*)alloc(NN * sizeof(float));
    float* dinv2 = (float*)alloc(NN * sizeof(float));
    float* a_s = (float*)alloc(NN * sizeof(float));
    float* a_d = (float*)alloc(NN * sizeof(float));
    float* vs = (float*)alloc(HH * sizeof(float));
    float* vd = (float*)alloc(HH * sizeof(float));
    u16* Wt0 = (u16*)alloc(8192 * sizeof(u16));    // [128][64]
    u16* Wt1 = (u16*)alloc(16384 * sizeof(u16));   // [128][128]
    u16* Wt2 = (u16*)alloc(16384 * sizeof(u16));   // [128][128]
    u16* Wtr = (u16*)alloc(8192 * sizeof(u16));    // [64][128]
    u16* xb = (u16*)alloc((size_t)NN * FF * sizeof(u16));     // bf16(x)
    u16* xaggb = (u16*)alloc((size_t)NN * FF * sizeof(u16));  // bf16(Â x)
    u16* bufA = (u16*)alloc((size_t)NN * HH * sizeof(u16));
    u16* bufB = (u16*)alloc((size_t)NN * HH * sizeof(u16));

    hipMemsetAsync(cnt, 0, NN * sizeof(int), stream);

    // fused: edge count + x cast + weight transpose/cast + gemv
    build_k<<<(EE + PREP_ITEMS + 255) / 256, 256, 0, stream>>>(
        ecol, cnt, W0, W1, W2, Wr, Wg, att_src, att_dst, x,
        Wt0, Wt1, Wt2, Wtr, vs, vd, xb);
    chunksum_k<<<NCHUNK, 256, 0, stream>>>(cnt, chunk_sum, dinv1);
    chunkoff_k<<<1, 64, 0, stream>>>(chunk_sum, chunk_off, col_ptr);
    colptr_k<<<NCHUNK, 256, 0, stream>>>(cnt, chunk_off, col_ptr, cursor);
    fill_k<<<(EE + 255) / 256, 256, 0, stream>>>(erow, ecol, cursor, dinv1, meta1);

    int aggGrid = NN / 8;   // 12500, exact
    const int GG = 512;

    // layer 1: xagg = Â1 x ; x1 = relu(xagg@W0+b0) + fused a_s/a_d
    aggx_k<<<aggGrid, 256, 0, stream>>>(xb, col_ptr, meta1, dinv1, xaggb);
    gemm1_k<<<GG, 256, 0, stream>>>(xaggb, Wt0, b0, vs, vd, bufA, a_s, a_d);
    // attention
    attn_k<<<(NN + 31) / 32, 256, 0, stream>>>(col_ptr, meta1, a_s, a_d, alpha, dinv2);
    w2_k<<<(EE + 255) / 256, 256, 0, stream>>>(meta1, dinv2, alpha, meta2);
    // layer 2
    mfma_gemm_k<HH, HH, false><<<GG, 256, 0, stream>>>(bufA, Wt1, nullptr, bufB);
    agg2_k<<<aggGrid, 256, 0, stream>>>(bufB, col_ptr, meta2, dinv2, b1, bufA);
    // layer 3
    mfma_gemm_k<HH, HH, false><<<GG, 256, 0, stream>>>(bufA, Wt2, nullptr, bufB);
    agg2_k<<<aggGrid, 256, 0, stream>>>(bufB, col_ptr, meta2, dinv2, b2, bufA);
    // readout
    mfma_gemm_k<HH, FF, true><<<GG, 256, 0, stream>>>(bufA, Wtr, br, out);
}

// Round 11
// 243.290 us; speedup vs baseline: 1.3508x; 1.0187x over previous
//
#include <hip/hip_runtime.h>
#include <hip/hip_bf16.h>
#include <hip/hip_fp16.h>
#include <math.h>

#define NN 100000
#define EE 600000
#define FF 64
#define HH 128
#define CHUNK 1024
#define NCHUNK ((NN + CHUNK - 1) / CHUNK)   // 98
#define NCHUNKS_M (NN / 16)                 // 6250 (exact)
#define PREP_ITEMS (NN * FF / 4 + 49280)

typedef unsigned short u16;
typedef unsigned int u32;
typedef __attribute__((ext_vector_type(8))) short bf16x8;
typedef __attribute__((ext_vector_type(4))) float f32x4;

__device__ __forceinline__ u16 f2bf(float f) {
    __hip_bfloat16 h = __float2bfloat16(f);
    return *(u16*)&h;
}
__device__ __forceinline__ float bf2f(u16 u) {
    unsigned int t = ((unsigned int)u) << 16;
    return *(float*)&t;
}
// meta pack: src in bits [31:15], fp16 weight (sign dropped, w>0) in [14:0]
__device__ __forceinline__ u32 enc_meta(int r, float w) {
    u16 hb = __half_as_ushort(__float2half(w));
    return ((u32)r << 15) | (hb & 0x7fffu);
}
__device__ __forceinline__ void dec_meta(u32 u, int& r, float& w) {
    r = (int)(u >> 15);
    w = __half2float(__ushort_as_half((u16)(u & 0x7fffu)));
}

// ---------------- fused: edge count (atomics) + weight/x prep ----------------

__global__ void build_k(const int* __restrict__ col, int* __restrict__ cnt,
                        const float* __restrict__ W0, const float* __restrict__ W1,
                        const float* __restrict__ W2, const float* __restrict__ Wr,
                        const float* __restrict__ Wg, const float* __restrict__ att_src,
                        const float* __restrict__ att_dst, const float* __restrict__ x,
                        u16* __restrict__ Wt0, u16* __restrict__ Wt1,
                        u16* __restrict__ Wt2, u16* __restrict__ Wtr,
                        float* __restrict__ vs, float* __restrict__ vd,
                        u16* __restrict__ xb) {
    int i = blockIdx.x * 256 + threadIdx.x;
    if (i < EE) {
        atomicAdd(&cnt[col[i]], 1);
        return;
    }
    i -= EE;
    if (i < NN * FF / 4) {          // cast x -> bf16
        float4 v = ((const float4*)x)[i];
        ushort4 o;
        o.x = f2bf(v.x); o.y = f2bf(v.y); o.z = f2bf(v.z); o.w = f2bf(v.w);
        ((ushort4*)xb)[i] = o;
        return;
    }
    i -= NN * FF / 4;
    if (i < 8192) {                 // Wt0: [128][64] from W0[64][128]
        int n = i >> 6, k = i & 63;
        Wt0[i] = f2bf(W0[k * 128 + n]);
        return;
    }
    i -= 8192;
    if (i < 16384) {                // Wt1: [128][128]
        int n = i >> 7, k = i & 127;
        Wt1[i] = f2bf(W1[k * 128 + n]);
        return;
    }
    i -= 16384;
    if (i < 16384) {                // Wt2: [128][128]
        int n = i >> 7, k = i & 127;
        Wt2[i] = f2bf(W2[k * 128 + n]);
        return;
    }
    i -= 16384;
    if (i < 8192) {                 // Wtr: [64][128] from Wr[128][64]
        int n = i >> 7, k = i & 127;
        Wtr[i] = f2bf(Wr[k * 64 + n]);
        return;
    }
    i -= 8192;
    if (i < HH) {                   // gemv: vs/vd = Wg @ att_{src,dst}
        float s1 = 0.f, s2 = 0.f;
        for (int j = 0; j < HH; j++) {
            float w = Wg[i * HH + j];
            s1 += w * att_src[j];
            s2 += w * att_dst[j];
        }
        vs[i] = s1;
        vd[i] = s2;
    }
}

// chunk sums + dinv1 fused
__global__ void chunksum_k(const int* __restrict__ cnt, int* __restrict__ chunk_sum,
                           float* __restrict__ dinv1) {
    int b = blockIdx.x, t = threadIdx.x;
    int base = b * CHUNK + t * 4;
    int s = 0;
    #pragma unroll
    for (int i = 0; i < 4; i++) {
        int idx = base + i;
        if (idx < NN) {
            int cv = cnt[idx];
            s += cv;
            dinv1[idx] = rsqrtf((float)cv + 1.0f);
        }
    }
    __shared__ int sm[4];
    for (int d = 32; d > 0; d >>= 1) s += __shfl_down(s, d);
    if ((t & 63) == 0) sm[t >> 6] = s;
    __syncthreads();
    if (t == 0) chunk_sum[b] = sm[0] + sm[1] + sm[2] + sm[3];
}

__global__ void chunkoff_k(const int* __restrict__ chunk_sum, int* __restrict__ chunk_off,
                           int* __restrict__ col_ptr) {
    if (threadIdx.x == 0) {
        int run = 0;
        for (int i = 0; i < NCHUNK; i++) { chunk_off[i] = run; run += chunk_sum[i]; }
        col_ptr[NN] = run;   // == EE
    }
}

__global__ void colptr_k(const int* __restrict__ cnt, const int* __restrict__ chunk_off,
                         int* __restrict__ col_ptr, int* __restrict__ cursor) {
    int b = blockIdx.x, t = threadIdx.x;
    int base = b * CHUNK + t * 4;
    int c[4]; int tot = 0;
    #pragma unroll
    for (int i = 0; i < 4; i++) { int idx = base + i; c[i] = (idx < NN) ? cnt[idx] : 0; tot += c[i]; }
    __shared__ int s[256];
    s[t] = tot;
    __syncthreads();
    for (int d = 1; d < 256; d <<= 1) {
        int v = (t >= d) ? s[t - d] : 0;
        __syncthreads();
        s[t] += v;
        __syncthreads();
    }
    int excl = s[t] - tot;
    int off = chunk_off[b] + excl;
    int pre = 0;
    #pragma unroll
    for (int i = 0; i < 4; i++) {
        int idx = base + i;
        if (idx < NN) {
            col_ptr[idx] = off + pre;
            cursor[idx] = off + pre;
        }
        pre += c[i];
    }
}

// fill CSR: single 4B scatter meta1 = enc(src, dinv1[r]*dinv1[c])
__global__ void fill_k(const int* __restrict__ row, const int* __restrict__ col,
                       int* __restrict__ cursor, const float* __restrict__ dinv1,
                       u32* __restrict__ meta1) {
    int e = blockIdx.x * 256 + threadIdx.x;
    if (e < EE) {
        int r = row[e], c = col[e];
        int slot = atomicAdd(&cursor[c], 1);
        meta1[slot] = enc_meta(r, dinv1[r] * dinv1[c]);
    }
}

// ---------------- layer-1 aggregate: 2 nodes/wave, 4 groups x 8 lanes, 16B/lane ----------------

__global__ __launch_bounds__(256) void aggx_k(
    const u16* __restrict__ xb, const int* __restrict__ col_ptr, const u32* __restrict__ meta1,
    const float* __restrict__ dinv1, u16* __restrict__ xout) {
    int wid = threadIdx.x >> 6, lane = threadIdx.x & 63;
    int sub = lane >> 5;
    int c = blockIdx.x * 8 + wid * 2 + sub;
    int hl = lane & 31;
    int g = hl >> 3;             // group 0..3
    int ch = (hl & 7) << 3;      // channel base 0,8,...,56
    int beg = col_ptr[c], end = col_ptr[c + 1];
    float acc[8] = {};

    int p = beg + g;
    int r = 0; float w = 0.f;
    if (p < end) dec_meta(meta1[p], r, w);
    while (p < end) {
        bf16x8 v = *(const bf16x8*)&xb[(size_t)r * FF + ch];
        int p2 = p + 4;
        int r2 = 0; float w2 = 0.f;
        if (p2 < end) dec_meta(meta1[p2], r2, w2);
        #pragma unroll
        for (int j = 0; j < 8; j++) acc[j] = fmaf(bf2f((u16)v[j]), w, acc[j]);
        p = p2; r = r2; w = w2;
    }
    // combine 4 groups within half-wave (xor 8, 16)
    #pragma unroll
    for (int j = 0; j < 8; j++) {
        acc[j] += __shfl_xor(acc[j], 8);
        acc[j] += __shfl_xor(acc[j], 16);
    }

    if (g == 0) {
        bf16x8 v = *(const bf16x8*)&xb[(size_t)c * FF + ch];
        float dc = dinv1[c];
        float ws = dc * dc;
        bf16x8 o;
        #pragma unroll
        for (int j = 0; j < 8; j++) {
            float t = fmaf(bf2f((u16)v[j]), ws, acc[j]);
            o[j] = (short)f2bf(t);
        }
        *(bf16x8*)&xout[(size_t)c * FF + ch] = o;
    }
}

// ---------------- GEMM1 fused: y1 = (relu(xagg@W0+b0)) @ W1, plus a_s/a_d ----------------
// x1 chunk (16x128) staged in a per-wave LDS slice (stride 136 u16 for alignment
// + bank spread); second MFMA chain reads it back as B-fragments. No barriers:
// each wave uses only its own slice.

__global__ __launch_bounds__(256) void gemm1_k(const u16* __restrict__ A,
                                               const u16* __restrict__ Wt0,
                                               const u16* __restrict__ Wt1,
                                               const float* __restrict__ bias,
                                               const float* __restrict__ vs, const float* __restrict__ vd,
                                               u16* __restrict__ Y, float* __restrict__ a_s,
                                               float* __restrict__ a_d) {
    constexpr int K = FF, N = HH, KK = K / 32, NT = N / 16, KK2 = HH / 32;
    constexpr int LSTRIDE = 136;
    __shared__ u16 lds[4][16 * LSTRIDE];
    int lane = threadIdx.x & 63, wid = threadIdx.x >> 6;
    int l15 = lane & 15, l4 = lane >> 4;
    int wg = blockIdx.x * 4 + wid;
    int nwaves = gridDim.x * 4;
    u16* myl = &lds[wid][0];

    bf16x8 a_frag[KK][NT];   // W0t fragments resident (64 VGPR)
    #pragma unroll
    for (int kk = 0; kk < KK; kk++)
        #pragma unroll
        for (int nt = 0; nt < NT; nt++)
            a_frag[kk][nt] = *(const bf16x8*)&Wt0[(size_t)(nt * 16 + l15) * K + kk * 32 + l4 * 8];

    for (int ch = wg; ch < NCHUNKS_M; ch += nwaves) {
        int row = ch * 16 + l15;
        bf16x8 b_frag[KK];
        #pragma unroll
        for (int kk = 0; kk < KK; kk++)
            b_frag[kk] = *(const bf16x8*)&A[(size_t)row * K + kk * 32 + l4 * 8];
        f32x4 acc[NT] = {};
        #pragma unroll
        for (int kk = 0; kk < KK; kk++)
            #pragma unroll
            for (int nt = 0; nt < NT; nt++)
                acc[nt] = __builtin_amdgcn_mfma_f32_16x16x32_bf16(a_frag[kk][nt], b_frag[kk],
                                                                  acc[nt], 0, 0, 0);
        float s1 = 0.f, s2 = 0.f;
        #pragma unroll
        for (int nt = 0; nt < NT; nt++) {
            f32x4 b4 = *(const f32x4*)&bias[nt * 16 + l4 * 4];
            f32x4 v4 = *(const f32x4*)&vs[nt * 16 + l4 * 4];
            f32x4 d4 = *(const f32x4*)&vd[nt * 16 + l4 * 4];
            float o0 = fmaxf(acc[nt][0] + b4[0], 0.f);
            float o1 = fmaxf(acc[nt][1] + b4[1], 0.f);
            float o2 = fmaxf(acc[nt][2] + b4[2], 0.f);
            float o3 = fmaxf(acc[nt][3] + b4[3], 0.f);
            ushort4 o;
            o.x = f2bf(o0); o.y = f2bf(o1); o.z = f2bf(o2); o.w = f2bf(o3);
            *(ushort4*)&myl[l15 * LSTRIDE + nt * 16 + l4 * 4] = o;
            s1 += o0 * v4[0] + o1 * v4[1] + o2 * v4[2] + o3 * v4[3];
            s2 += o0 * d4[0] + o1 * d4[1] + o2 * d4[2] + o3 * d4[3];
        }
        s1 += __shfl_xor(s1, 16); s1 += __shfl_xor(s1, 32);
        s2 += __shfl_xor(s2, 16); s2 += __shfl_xor(s2, 32);
        if (l4 == 0) {
            a_s[row] = s1;
            a_d[row] = s2;
        }
        // second GEMM: read x1 chunk back as B-fragments, multiply by W1t
        bf16x8 b2[KK2];
        #pragma unroll
        for (int kk2 = 0; kk2 < KK2; kk2++)
            b2[kk2] = *(const bf16x8*)&myl[l15 * LSTRIDE + kk2 * 32 + l4 * 8];
        f32x4 acc2[NT] = {};
        #pragma unroll
        for (int kk2 = 0; kk2 < KK2; kk2++)
            #pragma unroll
            for (int nt = 0; nt < NT; nt++) {
                bf16x8 w1f = *(const bf16x8*)&Wt1[(size_t)(nt * 16 + l15) * HH + kk2 * 32 + l4 * 8];
                acc2[nt] = __builtin_amdgcn_mfma_f32_16x16x32_bf16(w1f, b2[kk2], acc2[nt], 0, 0, 0);
            }
        #pragma unroll
        for (int nt = 0; nt < NT; nt++) {
            ushort4 o;
            o.x = f2bf(acc2[nt][0]);
            o.y = f2bf(acc2[nt][1]);
            o.z = f2bf(acc2[nt][2]);
            o.w = f2bf(acc2[nt][3]);
            *(ushort4*)&Y[(size_t)row * HH + nt * 16 + l4 * 4] = o;
        }
    }
}

// ---------------- MFMA GEMM (layer 3 + readout) ----------------

template <int K, int N, bool OUTF32>
__global__ __launch_bounds__(256) void mfma_gemm_k(const u16* __restrict__ A,
                                                   const u16* __restrict__ Wt,
                                                   const float* __restrict__ bias,
                                                   void* __restrict__ C_) {
    constexpr int KK = K / 32;
    constexpr int NT = N / 16;
    int lane = threadIdx.x & 63;
    int l15 = lane & 15, l4 = lane >> 4;
    int wg = blockIdx.x * 4 + (threadIdx.x >> 6);
    int nwaves = gridDim.x * 4;

    bf16x8 a_frag[KK][NT];
    #pragma unroll
    for (int kk = 0; kk < KK; kk++)
        #pragma unroll
        for (int nt = 0; nt < NT; nt++)
            a_frag[kk][nt] = *(const bf16x8*)&Wt[(size_t)(nt * 16 + l15) * K + kk * 32 + l4 * 8];

    f32x4 bias_f[NT];
    if (OUTF32) {
        #pragma unroll
        for (int nt = 0; nt < NT; nt++)
            bias_f[nt] = *(const f32x4*)&bias[nt * 16 + l4 * 4];
    }

    float* Cf = (float*)C_;
    u16* Cb = (u16*)C_;

    for (int ch = wg; ch < NCHUNKS_M; ch += nwaves) {
        int row = ch * 16 + l15;
        bf16x8 b_frag[KK];
        #pragma unroll
        for (int kk = 0; kk < KK; kk++)
            b_frag[kk] = *(const bf16x8*)&A[(size_t)row * K + kk * 32 + l4 * 8];
        f32x4 acc[NT] = {};
        #pragma unroll
        for (int kk = 0; kk < KK; kk++)
            #pragma unroll
            for (int nt = 0; nt < NT; nt++)
                acc[nt] = __builtin_amdgcn_mfma_f32_16x16x32_bf16(a_frag[kk][nt], b_frag[kk],
                                                                  acc[nt], 0, 0, 0);
        #pragma unroll
        for (int nt = 0; nt < NT; nt++) {
            int col = nt * 16 + l4 * 4;
            if (OUTF32) {
                float4 o;
                o.x = acc[nt][0] + bias_f[nt][0];
                o.y = acc[nt][1] + bias_f[nt][1];
                o.z = acc[nt][2] + bias_f[nt][2];
                o.w = acc[nt][3] + bias_f[nt][3];
                *(float4*)&Cf[(size_t)row * N + col] = o;
            } else {
                ushort4 o;
                o.x = f2bf(acc[nt][0]);
                o.y = f2bf(acc[nt][1]);
                o.z = f2bf(acc[nt][2]);
                o.w = f2bf(acc[nt][3]);
                *(ushort4*)&Cb[(size_t)row * N + col] = o;
            }
        }
    }
}

// ---------------- attention: 8 lanes per node, online softmax ----------------
// writes alpha[p] = softmax * dinv2[c]  (dinv2[r] applied by w2_k)

__global__ __launch_bounds__(256) void attn_k(const int* __restrict__ col_ptr,
                                              const u32* __restrict__ meta1,
                                              const float* __restrict__ a_s,
                                              const float* __restrict__ a_d,
                                              float* __restrict__ alpha,
                                              float* __restrict__ dinv2) {
    int lane = threadIdx.x & 63, wid = threadIdx.x >> 6;
    int grp = lane >> 3, idx = lane & 7;
    int c = blockIdx.x * 32 + wid * 8 + grp;
    if (c >= NN) return;
    int beg = col_ptr[c], end = col_ptr[c + 1];
    float ad = a_d[c];
    float es = a_s[c] + ad;
    es = (es > 0.f) ? es : 0.2f * es;
    float m = (idx == 0) ? es : -1e30f;
    float s = (idx == 0) ? 1.f : 0.f;
    for (int p = beg + idx; p < end; p += 8) {
        float e = a_s[meta1[p] >> 15] + ad;
        e = (e > 0.f) ? e : 0.2f * e;
        alpha[p] = e;
        float mn = fmaxf(m, e);
        s = s * expf(m - mn) + expf(e - mn);
        m = mn;
    }
    #pragma unroll
    for (int d = 1; d < 8; d <<= 1) {
        float mo = __shfl_xor(m, d);
        float so = __shfl_xor(s, d);
        float mn = fmaxf(m, mo);
        s = s * expf(m - mn) + so * expf(mo - mn);
        m = mn;
    }
    float inv = 1.f / s;
    float aself = expf(es - m) * inv;
    float d2 = rsqrtf(2.f - aself);
    if (idx == 0) dinv2[c] = d2;
    float sc = inv * d2;
    for (int p = beg + idx; p < end; p += 8)
        alpha[p] = expf(alpha[p] - m) * sc;
}

// meta2[p] = enc(src, alpha[p] * dinv2[src])
__global__ void w2_k(const u32* __restrict__ meta1, const float* __restrict__ dinv2,
                     const float* __restrict__ alpha, u32* __restrict__ meta2) {
    int p = blockIdx.x * 256 + threadIdx.x;
    if (p < EE) {
        u32 u = meta1[p];
        int r = (int)(u >> 15);
        float w = alpha[p] * dinv2[r];
        u16 hb = __half_as_ushort(__float2half(w));
        meta2[p] = (u & 0xffff8000u) | (hb & 0x7fffu);
    }
}

// ---------------- layers 2/3 aggregate: 2 nodes/wave, 2 groups x 16 lanes x 2 streams ----------------

__global__ __launch_bounds__(256) void agg2_k(
    const u16* __restrict__ xw, const int* __restrict__ col_ptr, const u32* __restrict__ meta2,
    const float* __restrict__ dinv2, const float* __restrict__ bias, u16* __restrict__ xout) {
    int wid = threadIdx.x >> 6, lane = threadIdx.x & 63;
    int sub = lane >> 5;
    int c = blockIdx.x * 8 + wid * 2 + sub;
    int hl = lane & 31;
    int g = hl >> 4;              // group 0..1
    int ch = (hl & 15) << 3;      // channel base 0,8,...,120
    int beg = col_ptr[c], end = col_ptr[c + 1];
    float acc[8] = {};

    int pA = beg + g, pB = pA + 2;
    int rA = 0, rB = 0; float wA = 0.f, wB = 0.f;
    if (pA < end) dec_meta(meta2[pA], rA, wA);
    if (pB < end) dec_meta(meta2[pB], rB, wB);
    while (pA < end) {
        bool hb = pB < end;
        bf16x8 vA = *(const bf16x8*)&xw[(size_t)rA * HH + ch];
        bf16x8 vB;
        if (hb) vB = *(const bf16x8*)&xw[(size_t)rB * HH + ch];
        int pA2 = pA + 4, pB2 = pB + 4;
        int rA2 = 0, rB2 = 0; float wA2 = 0.f, wB2 = 0.f;
        if (pA2 < end) dec_meta(meta2[pA2], rA2, wA2);
        if (pB2 < end) dec_meta(meta2[pB2], rB2, wB2);
        #pragma unroll
        for (int j = 0; j < 8; j++) acc[j] = fmaf(bf2f((u16)vA[j]), wA, acc[j]);
        if (hb) {
            #pragma unroll
            for (int j = 0; j < 8; j++) acc[j] = fmaf(bf2f((u16)vB[j]), wB, acc[j]);
        }
        pA = pA2; pB = pB2; rA = rA2; rB = rB2; wA = wA2; wB = wB2;
    }
    // combine 2 groups within half-wave (xor 16)
    #pragma unroll
    for (int j = 0; j < 8; j++) acc[j] += __shfl_xor(acc[j], 16);

    if (g == 0) {
        bf16x8 v = *(const bf16x8*)&xw[(size_t)c * HH + ch];
        float dc = dinv2[c];
        float ws = dc * dc;
        f32x4 b4a = *(const f32x4*)&bias[ch];
        f32x4 b4b = *(const f32x4*)&bias[ch + 4];
        bf16x8 o;
        #pragma unroll
        for (int j = 0; j < 8; j++) {
            float bj = (j < 4) ? b4a[j] : b4b[j - 4];
            float t = fmaxf(fmaf(bf2f((u16)v[j]), ws, acc[j]) + bj, 0.f);
            o[j] = (short)f2bf(t);
        }
        *(bf16x8*)&xout[(size_t)c * HH + ch] = o;
    }
}

// ---------------- launch ----------------

extern "C" void kernel_launch(void* const* d_in, const int* in_sizes, int n_in,
                              void* d_out, int out_size, void* d_ws, size_t ws_size,
                              hipStream_t stream) {
    const float* x = (const float*)d_in[0];
    const int* eidx = (const int*)d_in[1];     // [2][E]: row, col
    const float* W0 = (const float*)d_in[3];
    const float* b0 = (const float*)d_in[4];
    const float* Wg = (const float*)d_in[5];
    const float* att_src = (const float*)d_in[6];
    const float* att_dst = (const float*)d_in[7];
    const float* W1 = (const float*)d_in[8];
    const float* b1 = (const float*)d_in[9];
    const float* W2 = (const float*)d_in[10];
    const float* b2 = (const float*)d_in[11];
    const float* Wr = (const float*)d_in[12];
    const float* br = (const float*)d_in[13];
    float* out = (float*)d_out;

    const int* erow = eidx;
    const int* ecol = eidx + EE;

    char* p = (char*)d_ws;
    auto alloc = [&](size_t bytes) {
        void* r = (void*)p;
        p += (bytes + 255) & ~(size_t)255;
        return r;
    };
    int* col_ptr = (int*)alloc((NN + 1) * sizeof(int));
    u32* meta1 = (u32*)alloc(EE * sizeof(u32));
    u32* meta2 = (u32*)alloc(EE * sizeof(u32));
    int* cnt = (int*)alloc(NN * sizeof(int));
    int* cursor = (int*)alloc(NN * sizeof(int));
    int* chunk_sum = (int*)alloc(128 * sizeof(int));
    int* chunk_off = (int*)alloc(128 * sizeof(int));
    float* alpha = (float*)alloc(EE * sizeof(float));
    float* dinv1 = (float*)alloc(NN * sizeof(float));
    float* dinv2 = (float*)alloc(NN * sizeof(float));
    float* a_s = (float*)alloc(NN * sizeof(float));
    float* a_d = (float*)alloc(NN * sizeof(float));
    float* vs = (float*)alloc(HH * sizeof(float));
    float* vd = (float*)alloc(HH * sizeof(float));
    u16* Wt0 = (u16*)alloc(8192 * sizeof(u16));    // [128][64]
    u16* Wt1 = (u16*)alloc(16384 * sizeof(u16));   // [128][128]
    u16* Wt2 = (u16*)alloc(16384 * sizeof(u16));   // [128][128]
    u16* Wtr = (u16*)alloc(8192 * sizeof(u16));    // [64][128]
    u16* xb = (u16*)alloc((size_t)NN * FF * sizeof(u16));     // bf16(x)
    u16* xaggb = (u16*)alloc((size_t)NN * FF * sizeof(u16));  // bf16(Â x)
    u16* bufA = (u16*)alloc((size_t)NN * HH * sizeof(u16));
    u16* bufB = (u16*)alloc((size_t)NN * HH * sizeof(u16));

    hipMemsetAsync(cnt, 0, NN * sizeof(int), stream);

    // fused: edge count + x cast + weight transpose/cast + gemv
    build_k<<<(EE + PREP_ITEMS + 255) / 256, 256, 0, stream>>>(
        ecol, cnt, W0, W1, W2, Wr, Wg, att_src, att_dst, x,
        Wt0, Wt1, Wt2, Wtr, vs, vd, xb);
    chunksum_k<<<NCHUNK, 256, 0, stream>>>(cnt, chunk_sum, dinv1);
    chunkoff_k<<<1, 64, 0, stream>>>(chunk_sum, chunk_off, col_ptr);
    colptr_k<<<NCHUNK, 256, 0, stream>>>(cnt, chunk_off, col_ptr, cursor);
    fill_k<<<(EE + 255) / 256, 256, 0, stream>>>(erow, ecol, cursor, dinv1, meta1);

    int aggGrid = NN / 8;   // 12500, exact
    const int GG = 512;

    // layer 1: xagg = Â1 x ; y1 = relu(xagg@W0+b0)@W1 fused, + a_s/a_d
    aggx_k<<<aggGrid, 256, 0, stream>>>(xb, col_ptr, meta1, dinv1, xaggb);
    gemm1_k<<<GG, 256, 0, stream>>>(xaggb, Wt0, Wt1, b0, vs, vd, bufB, a_s, a_d);
    // attention
    attn_k<<<(NN + 31) / 32, 256, 0, stream>>>(col_ptr, meta1, a_s, a_d, alpha, dinv2);
    w2_k<<<(EE + 255) / 256, 256, 0, stream>>>(meta1, dinv2, alpha, meta2);
    // layer 2: x2 = agg(y1)
    agg2_k<<<aggGrid, 256, 0, stream>>>(bufB, col_ptr, meta2, dinv2, b1, bufA);
    // layer 3: y2 = x2@W2 ; x3 = agg(y2)
    mfma_gemm_k<HH, HH, false><<<GG, 256, 0, stream>>>(bufA, Wt2, nullptr, bufB);
    agg2_k<<<aggGrid, 256, 0, stream>>>(bufB, col_ptr, meta2, dinv2, b2, bufA);
    // readout
    mfma_gemm_k<HH, FF, true><<<GG, 256, 0, stream>>>(bufA, Wtr, br, out);
}

// Round 12
// 242.242 us; speedup vs baseline: 1.3567x; 1.0043x over previous
//
#include <hip/hip_runtime.h>
#include <hip/hip_bf16.h>
#include <hip/hip_fp16.h>
#include <math.h>

#define NN 100000
#define EE 600000
#define FF 64
#define HH 128
#define CHUNK 1024
#define NCHUNK ((NN + CHUNK - 1) / CHUNK)   // 98
#define NCHUNKS_M (NN / 16)                 // 6250 (exact)
#define PREP_ITEMS (NN * FF / 4 + 49280)

typedef unsigned short u16;
typedef unsigned int u32;
typedef __attribute__((ext_vector_type(8))) short bf16x8;
typedef __attribute__((ext_vector_type(4))) float f32x4;

__device__ __forceinline__ u16 f2bf(float f) {
    __hip_bfloat16 h = __float2bfloat16(f);
    return *(u16*)&h;
}
__device__ __forceinline__ float bf2f(u16 u) {
    unsigned int t = ((unsigned int)u) << 16;
    return *(float*)&t;
}
// meta pack: src in bits [31:15], fp16 weight (sign dropped, w>0) in [14:0]
__device__ __forceinline__ u32 enc_meta(int r, float w) {
    u16 hb = __half_as_ushort(__float2half(w));
    return ((u32)r << 15) | (hb & 0x7fffu);
}
__device__ __forceinline__ void dec_meta(u32 u, int& r, float& w) {
    r = (int)(u >> 15);
    w = __half2float(__ushort_as_half((u16)(u & 0x7fffu)));
}

// ---------------- fused: edge count (atomics) + weight/x prep ----------------

__global__ void build_k(const int* __restrict__ col, int* __restrict__ cnt,
                        const float* __restrict__ W0, const float* __restrict__ W1,
                        const float* __restrict__ W2, const float* __restrict__ Wr,
                        const float* __restrict__ Wg, const float* __restrict__ att_src,
                        const float* __restrict__ att_dst, const float* __restrict__ x,
                        u16* __restrict__ Wt0, u16* __restrict__ Wt1,
                        u16* __restrict__ Wt2, u16* __restrict__ Wtr,
                        float* __restrict__ vs, float* __restrict__ vd,
                        u16* __restrict__ xb) {
    int i = blockIdx.x * 256 + threadIdx.x;
    if (i < EE) {
        atomicAdd(&cnt[col[i]], 1);
        return;
    }
    i -= EE;
    if (i < NN * FF / 4) {          // cast x -> bf16
        float4 v = ((const float4*)x)[i];
        ushort4 o;
        o.x = f2bf(v.x); o.y = f2bf(v.y); o.z = f2bf(v.z); o.w = f2bf(v.w);
        ((ushort4*)xb)[i] = o;
        return;
    }
    i -= NN * FF / 4;
    if (i < 8192) {                 // Wt0: [128][64] from W0[64][128]
        int n = i >> 6, k = i & 63;
        Wt0[i] = f2bf(W0[k * 128 + n]);
        return;
    }
    i -= 8192;
    if (i < 16384) {                // Wt1: [128][128]
        int n = i >> 7, k = i & 127;
        Wt1[i] = f2bf(W1[k * 128 + n]);
        return;
    }
    i -= 16384;
    if (i < 16384) {                // Wt2: [128][128]
        int n = i >> 7, k = i & 127;
        Wt2[i] = f2bf(W2[k * 128 + n]);
        return;
    }
    i -= 16384;
    if (i < 8192) {                 // Wtr: [64][128] from Wr[128][64]
        int n = i >> 7, k = i & 127;
        Wtr[i] = f2bf(Wr[k * 64 + n]);
        return;
    }
    i -= 8192;
    if (i < HH) {                   // gemv: vs/vd = Wg @ att_{src,dst}
        float s1 = 0.f, s2 = 0.f;
        for (int j = 0; j < HH; j++) {
            float w = Wg[i * HH + j];
            s1 += w * att_src[j];
            s2 += w * att_dst[j];
        }
        vs[i] = s1;
        vd[i] = s2;
    }
}

// chunk sums + dinv1 fused
__global__ void chunksum_k(const int* __restrict__ cnt, int* __restrict__ chunk_sum,
                           float* __restrict__ dinv1) {
    int b = blockIdx.x, t = threadIdx.x;
    int base = b * CHUNK + t * 4;
    int s = 0;
    #pragma unroll
    for (int i = 0; i < 4; i++) {
        int idx = base + i;
        if (idx < NN) {
            int cv = cnt[idx];
            s += cv;
            dinv1[idx] = rsqrtf((float)cv + 1.0f);
        }
    }
    __shared__ int sm[4];
    for (int d = 32; d > 0; d >>= 1) s += __shfl_down(s, d);
    if ((t & 63) == 0) sm[t >> 6] = s;
    __syncthreads();
    if (t == 0) chunk_sum[b] = sm[0] + sm[1] + sm[2] + sm[3];
}

__global__ void chunkoff_k(const int* __restrict__ chunk_sum, int* __restrict__ chunk_off,
                           int* __restrict__ col_ptr) {
    if (threadIdx.x == 0) {
        int run = 0;
        for (int i = 0; i < NCHUNK; i++) { chunk_off[i] = run; run += chunk_sum[i]; }
        col_ptr[NN] = run;   // == EE
    }
}

__global__ void colptr_k(const int* __restrict__ cnt, const int* __restrict__ chunk_off,
                         int* __restrict__ col_ptr, int* __restrict__ cursor) {
    int b = blockIdx.x, t = threadIdx.x;
    int base = b * CHUNK + t * 4;
    int c[4]; int tot = 0;
    #pragma unroll
    for (int i = 0; i < 4; i++) { int idx = base + i; c[i] = (idx < NN) ? cnt[idx] : 0; tot += c[i]; }
    __shared__ int s[256];
    s[t] = tot;
    __syncthreads();
    for (int d = 1; d < 256; d <<= 1) {
        int v = (t >= d) ? s[t - d] : 0;
        __syncthreads();
        s[t] += v;
        __syncthreads();
    }
    int excl = s[t] - tot;
    int off = chunk_off[b] + excl;
    int pre = 0;
    #pragma unroll
    for (int i = 0; i < 4; i++) {
        int idx = base + i;
        if (idx < NN) {
            col_ptr[idx] = off + pre;
            cursor[idx] = off + pre;
        }
        pre += c[i];
    }
}

// fill CSR: single 4B scatter meta1 = enc(src, dinv1[r]*dinv1[c])
__global__ void fill_k(const int* __restrict__ row, const int* __restrict__ col,
                       int* __restrict__ cursor, const float* __restrict__ dinv1,
                       u32* __restrict__ meta1) {
    int e = blockIdx.x * 256 + threadIdx.x;
    if (e < EE) {
        int r = row[e], c = col[e];
        int slot = atomicAdd(&cursor[c], 1);
        meta1[slot] = enc_meta(r, dinv1[r] * dinv1[c]);
    }
}

// ---------------- layer-1 aggregate: 2 nodes/wave, 4 groups x 8 lanes x 2 streams ----------------

__global__ __launch_bounds__(256, 8) void aggx_k(
    const u16* __restrict__ xb, const int* __restrict__ col_ptr, const u32* __restrict__ meta1,
    const float* __restrict__ dinv1, u16* __restrict__ xout) {
    int wid = threadIdx.x >> 6, lane = threadIdx.x & 63;
    int sub = lane >> 5;
    int c = blockIdx.x * 8 + wid * 2 + sub;
    int hl = lane & 31;
    int g = hl >> 3;             // group 0..3
    int ch = (hl & 7) << 3;      // channel base 0,8,...,56
    int beg = col_ptr[c], end = col_ptr[c + 1];
    float acc[8] = {};

    int pA = beg + g, pB = pA + 4;
    int rA = 0, rB = 0; float wA = 0.f, wB = 0.f;
    if (pA < end) dec_meta(meta1[pA], rA, wA);
    if (pB < end) dec_meta(meta1[pB], rB, wB);
    while (pA < end) {
        bool hb = pB < end;
        bf16x8 vA = *(const bf16x8*)&xb[(size_t)rA * FF + ch];
        bf16x8 vB;
        if (hb) vB = *(const bf16x8*)&xb[(size_t)rB * FF + ch];
        int pA2 = pA + 8, pB2 = pB + 8;
        int rA2 = 0, rB2 = 0; float wA2 = 0.f, wB2 = 0.f;
        if (pA2 < end) dec_meta(meta1[pA2], rA2, wA2);
        if (pB2 < end) dec_meta(meta1[pB2], rB2, wB2);
        #pragma unroll
        for (int j = 0; j < 8; j++) acc[j] = fmaf(bf2f((u16)vA[j]), wA, acc[j]);
        if (hb) {
            #pragma unroll
            for (int j = 0; j < 8; j++) acc[j] = fmaf(bf2f((u16)vB[j]), wB, acc[j]);
        }
        pA = pA2; pB = pB2; rA = rA2; rB = rB2; wA = wA2; wB = wB2;
    }
    // combine 4 groups within half-wave (xor 8, 16)
    #pragma unroll
    for (int j = 0; j < 8; j++) {
        acc[j] += __shfl_xor(acc[j], 8);
        acc[j] += __shfl_xor(acc[j], 16);
    }

    if (g == 0) {
        bf16x8 v = *(const bf16x8*)&xb[(size_t)c * FF + ch];
        float dc = dinv1[c];
        float ws = dc * dc;
        bf16x8 o;
        #pragma unroll
        for (int j = 0; j < 8; j++) {
            float t = fmaf(bf2f((u16)v[j]), ws, acc[j]);
            o[j] = (short)f2bf(t);
        }
        *(bf16x8*)&xout[(size_t)c * FF + ch] = o;
    }
}

// ---------------- GEMM1 fused: y1 = (relu(xagg@W0+b0)) @ W1, plus a_s/a_d ----------------

__global__ __launch_bounds__(256) void gemm1_k(const u16* __restrict__ A,
                                               const u16* __restrict__ Wt0,
                                               const u16* __restrict__ Wt1,
                                               const float* __restrict__ bias,
                                               const float* __restrict__ vs, const float* __restrict__ vd,
                                               u16* __restrict__ Y, float* __restrict__ a_s,
                                               float* __restrict__ a_d) {
    constexpr int K = FF, N = HH, KK = K / 32, NT = N / 16, KK2 = HH / 32;
    constexpr int LSTRIDE = 136;
    __shared__ u16 lds[4][16 * LSTRIDE];
    int lane = threadIdx.x & 63, wid = threadIdx.x >> 6;
    int l15 = lane & 15, l4 = lane >> 4;
    int wg = blockIdx.x * 4 + wid;
    int nwaves = gridDim.x * 4;
    u16* myl = &lds[wid][0];

    bf16x8 a_frag[KK][NT];   // W0t fragments resident
    #pragma unroll
    for (int kk = 0; kk < KK; kk++)
        #pragma unroll
        for (int nt = 0; nt < NT; nt++)
            a_frag[kk][nt] = *(const bf16x8*)&Wt0[(size_t)(nt * 16 + l15) * K + kk * 32 + l4 * 8];

    for (int ch = wg; ch < NCHUNKS_M; ch += nwaves) {
        int row = ch * 16 + l15;
        bf16x8 b_frag[KK];
        #pragma unroll
        for (int kk = 0; kk < KK; kk++)
            b_frag[kk] = *(const bf16x8*)&A[(size_t)row * K + kk * 32 + l4 * 8];
        f32x4 acc[NT] = {};
        #pragma unroll
        for (int kk = 0; kk < KK; kk++)
            #pragma unroll
            for (int nt = 0; nt < NT; nt++)
                acc[nt] = __builtin_amdgcn_mfma_f32_16x16x32_bf16(a_frag[kk][nt], b_frag[kk],
                                                                  acc[nt], 0, 0, 0);
        float s1 = 0.f, s2 = 0.f;
        #pragma unroll
        for (int nt = 0; nt < NT; nt++) {
            f32x4 b4 = *(const f32x4*)&bias[nt * 16 + l4 * 4];
            f32x4 v4 = *(const f32x4*)&vs[nt * 16 + l4 * 4];
            f32x4 d4 = *(const f32x4*)&vd[nt * 16 + l4 * 4];
            float o0 = fmaxf(acc[nt][0] + b4[0], 0.f);
            float o1 = fmaxf(acc[nt][1] + b4[1], 0.f);
            float o2 = fmaxf(acc[nt][2] + b4[2], 0.f);
            float o3 = fmaxf(acc[nt][3] + b4[3], 0.f);
            ushort4 o;
            o.x = f2bf(o0); o.y = f2bf(o1); o.z = f2bf(o2); o.w = f2bf(o3);
            *(ushort4*)&myl[l15 * LSTRIDE + nt * 16 + l4 * 4] = o;
            s1 += o0 * v4[0] + o1 * v4[1] + o2 * v4[2] + o3 * v4[3];
            s2 += o0 * d4[0] + o1 * d4[1] + o2 * d4[2] + o3 * d4[3];
        }
        s1 += __shfl_xor(s1, 16); s1 += __shfl_xor(s1, 32);
        s2 += __shfl_xor(s2, 16); s2 += __shfl_xor(s2, 32);
        if (l4 == 0) {
            a_s[row] = s1;
            a_d[row] = s2;
        }
        // second GEMM: read x1 chunk back as B-fragments, multiply by W1t
        bf16x8 b2[KK2];
        #pragma unroll
        for (int kk2 = 0; kk2 < KK2; kk2++)
            b2[kk2] = *(const bf16x8*)&myl[l15 * LSTRIDE + kk2 * 32 + l4 * 8];
        f32x4 acc2[NT] = {};
        #pragma unroll
        for (int kk2 = 0; kk2 < KK2; kk2++)
            #pragma unroll
            for (int nt = 0; nt < NT; nt++) {
                bf16x8 w1f = *(const bf16x8*)&Wt1[(size_t)(nt * 16 + l15) * HH + kk2 * 32 + l4 * 8];
                acc2[nt] = __builtin_amdgcn_mfma_f32_16x16x32_bf16(w1f, b2[kk2], acc2[nt], 0, 0, 0);
            }
        #pragma unroll
        for (int nt = 0; nt < NT; nt++) {
            ushort4 o;
            o.x = f2bf(acc2[nt][0]);
            o.y = f2bf(acc2[nt][1]);
            o.z = f2bf(acc2[nt][2]);
            o.w = f2bf(acc2[nt][3]);
            *(ushort4*)&Y[(size_t)row * HH + nt * 16 + l4 * 4] = o;
        }
    }
}

// ---------------- MFMA GEMM (layer 3 + readout) ----------------

template <int K, int N, bool OUTF32>
__global__ __launch_bounds__(256) void mfma_gemm_k(const u16* __restrict__ A,
                                                   const u16* __restrict__ Wt,
                                                   const float* __restrict__ bias,
                                                   void* __restrict__ C_) {
    constexpr int KK = K / 32;
    constexpr int NT = N / 16;
    int lane = threadIdx.x & 63;
    int l15 = lane & 15, l4 = lane >> 4;
    int wg = blockIdx.x * 4 + (threadIdx.x >> 6);
    int nwaves = gridDim.x * 4;

    bf16x8 a_frag[KK][NT];
    #pragma unroll
    for (int kk = 0; kk < KK; kk++)
        #pragma unroll
        for (int nt = 0; nt < NT; nt++)
            a_frag[kk][nt] = *(const bf16x8*)&Wt[(size_t)(nt * 16 + l15) * K + kk * 32 + l4 * 8];

    f32x4 bias_f[NT];
    if (OUTF32) {
        #pragma unroll
        for (int nt = 0; nt < NT; nt++)
            bias_f[nt] = *(const f32x4*)&bias[nt * 16 + l4 * 4];
    }

    float* Cf = (float*)C_;
    u16* Cb = (u16*)C_;

    for (int ch = wg; ch < NCHUNKS_M; ch += nwaves) {
        int row = ch * 16 + l15;
        bf16x8 b_frag[KK];
        #pragma unroll
        for (int kk = 0; kk < KK; kk++)
            b_frag[kk] = *(const bf16x8*)&A[(size_t)row * K + kk * 32 + l4 * 8];
        f32x4 acc[NT] = {};
        #pragma unroll
        for (int kk = 0; kk < KK; kk++)
            #pragma unroll
            for (int nt = 0; nt < NT; nt++)
                acc[nt] = __builtin_amdgcn_mfma_f32_16x16x32_bf16(a_frag[kk][nt], b_frag[kk],
                                                                  acc[nt], 0, 0, 0);
        #pragma unroll
        for (int nt = 0; nt < NT; nt++) {
            int col = nt * 16 + l4 * 4;
            if (OUTF32) {
                float4 o;
                o.x = acc[nt][0] + bias_f[nt][0];
                o.y = acc[nt][1] + bias_f[nt][1];
                o.z = acc[nt][2] + bias_f[nt][2];
                o.w = acc[nt][3] + bias_f[nt][3];
                *(float4*)&Cf[(size_t)row * N + col] = o;
            } else {
                ushort4 o;
                o.x = f2bf(acc[nt][0]);
                o.y = f2bf(acc[nt][1]);
                o.z = f2bf(acc[nt][2]);
                o.w = f2bf(acc[nt][3]);
                *(ushort4*)&Cb[(size_t)row * N + col] = o;
            }
        }
    }
}

// ---------------- attention: 8 lanes per node, online softmax ----------------
// writes alpha[p] = softmax * dinv2[c]  (dinv2[r] applied by w2_k)

__global__ __launch_bounds__(256) void attn_k(const int* __restrict__ col_ptr,
                                              const u32* __restrict__ meta1,
                                              const float* __restrict__ a_s,
                                              const float* __restrict__ a_d,
                                              float* __restrict__ alpha,
                                              float* __restrict__ dinv2) {
    int lane = threadIdx.x & 63, wid = threadIdx.x >> 6;
    int grp = lane >> 3, idx = lane & 7;
    int c = blockIdx.x * 32 + wid * 8 + grp;
    if (c >= NN) return;
    int beg = col_ptr[c], end = col_ptr[c + 1];
    float ad = a_d[c];
    float es = a_s[c] + ad;
    es = (es > 0.f) ? es : 0.2f * es;
    float m = (idx == 0) ? es : -1e30f;
    float s = (idx == 0) ? 1.f : 0.f;
    for (int p = beg + idx; p < end; p += 8) {
        float e = a_s[meta1[p] >> 15] + ad;
        e = (e > 0.f) ? e : 0.2f * e;
        alpha[p] = e;
        float mn = fmaxf(m, e);
        s = s * expf(m - mn) + expf(e - mn);
        m = mn;
    }
    #pragma unroll
    for (int d = 1; d < 8; d <<= 1) {
        float mo = __shfl_xor(m, d);
        float so = __shfl_xor(s, d);
        float mn = fmaxf(m, mo);
        s = s * expf(m - mn) + so * expf(mo - mn);
        m = mn;
    }
    float inv = 1.f / s;
    float aself = expf(es - m) * inv;
    float d2 = rsqrtf(2.f - aself);
    if (idx == 0) dinv2[c] = d2;
    float sc = inv * d2;
    for (int p = beg + idx; p < end; p += 8)
        alpha[p] = expf(alpha[p] - m) * sc;
}

// meta2[p] = enc(src, alpha[p] * dinv2[src])
__global__ void w2_k(const u32* __restrict__ meta1, const float* __restrict__ dinv2,
                     const float* __restrict__ alpha, u32* __restrict__ meta2) {
    int p = blockIdx.x * 256 + threadIdx.x;
    if (p < EE) {
        u32 u = meta1[p];
        int r = (int)(u >> 15);
        float w = alpha[p] * dinv2[r];
        u16 hb = __half_as_ushort(__float2half(w));
        meta2[p] = (u & 0xffff8000u) | (hb & 0x7fffu);
    }
}

// ---------------- layers 2/3 aggregate: 2 nodes/wave, 2 groups x 16 lanes x 3 streams ----------------

__global__ __launch_bounds__(256, 8) void agg2_k(
    const u16* __restrict__ xw, const int* __restrict__ col_ptr, const u32* __restrict__ meta2,
    const float* __restrict__ dinv2, const float* __restrict__ bias, u16* __restrict__ xout) {
    int wid = threadIdx.x >> 6, lane = threadIdx.x & 63;
    int sub = lane >> 5;
    int c = blockIdx.x * 8 + wid * 2 + sub;
    int hl = lane & 31;
    int g = hl >> 4;              // group 0..1
    int ch = (hl & 15) << 3;      // channel base 0,8,...,120
    int beg = col_ptr[c], end = col_ptr[c + 1];
    float acc[8] = {};

    int pA = beg + g, pB = pA + 2, pC = pA + 4;
    int rA = 0, rB = 0, rC = 0; float wA = 0.f, wB = 0.f, wC = 0.f;
    if (pA < end) dec_meta(meta2[pA], rA, wA);
    if (pB < end) dec_meta(meta2[pB], rB, wB);
    if (pC < end) dec_meta(meta2[pC], rC, wC);
    while (pA < end) {
        bool hb = pB < end, hc = pC < end;
        bf16x8 vA = *(const bf16x8*)&xw[(size_t)rA * HH + ch];
        bf16x8 vB, vC;
        if (hb) vB = *(const bf16x8*)&xw[(size_t)rB * HH + ch];
        if (hc) vC = *(const bf16x8*)&xw[(size_t)rC * HH + ch];
        int pA2 = pA + 6, pB2 = pB + 6, pC2 = pC + 6;
        int rA2 = 0, rB2 = 0, rC2 = 0; float wA2 = 0.f, wB2 = 0.f, wC2 = 0.f;
        if (pA2 < end) dec_meta(meta2[pA2], rA2, wA2);
        if (pB2 < end) dec_meta(meta2[pB2], rB2, wB2);
        if (pC2 < end) dec_meta(meta2[pC2], rC2, wC2);
        #pragma unroll
        for (int j = 0; j < 8; j++) acc[j] = fmaf(bf2f((u16)vA[j]), wA, acc[j]);
        if (hb) {
            #pragma unroll
            for (int j = 0; j < 8; j++) acc[j] = fmaf(bf2f((u16)vB[j]), wB, acc[j]);
        }
        if (hc) {
            #pragma unroll
            for (int j = 0; j < 8; j++) acc[j] = fmaf(bf2f((u16)vC[j]), wC, acc[j]);
        }
        pA = pA2; pB = pB2; pC = pC2;
        rA = rA2; rB = rB2; rC = rC2;
        wA = wA2; wB = wB2; wC = wC2;
    }
    // combine 2 groups within half-wave (xor 16)
    #pragma unroll
    for (int j = 0; j < 8; j++) acc[j] += __shfl_xor(acc[j], 16);

    if (g == 0) {
        bf16x8 v = *(const bf16x8*)&xw[(size_t)c * HH + ch];
        float dc = dinv2[c];
        float ws = dc * dc;
        f32x4 b4a = *(const f32x4*)&bias[ch];
        f32x4 b4b = *(const f32x4*)&bias[ch + 4];
        bf16x8 o;
        #pragma unroll
        for (int j = 0; j < 8; j++) {
            float bj = (j < 4) ? b4a[j] : b4b[j - 4];
            float t = fmaxf(fmaf(bf2f((u16)v[j]), ws, acc[j]) + bj, 0.f);
            o[j] = (short)f2bf(t);
        }
        *(bf16x8*)&xout[(size_t)c * HH + ch] = o;
    }
}

// ---------------- launch ----------------

extern "C" void kernel_launch(void* const* d_in, const int* in_sizes, int n_in,
                              void* d_out, int out_size, void* d_ws, size_t ws_size,
                              hipStream_t stream) {
    const float* x = (const float*)d_in[0];
    const int* eidx = (const int*)d_in[1];     // [2][E]: row, col
    const float* W0 = (const float*)d_in[3];
    const float* b0 = (const float*)d_in[4];
    const float* Wg = (const float*)d_in[5];
    const float* att_src = (const float*)d_in[6];
    const float* att_dst = (const float*)d_in[7];
    const float* W1 = (const float*)d_in[8];
    const float* b1 = (const float*)d_in[9];
    const float* W2 = (const float*)d_in[10];
    const float* b2 = (const float*)d_in[11];
    const float* Wr = (const float*)d_in[12];
    const float* br = (const float*)d_in[13];
    float* out = (float*)d_out;

    const int* erow = eidx;
    const int* ecol = eidx + EE;

    char* p = (char*)d_ws;
    auto alloc = [&](size_t bytes) {
        void* r = (void*)p;
        p += (bytes + 255) & ~(size_t)255;
        return r;
    };
    int* col_ptr = (int*)alloc((NN + 1) * sizeof(int));
    u32* meta1 = (u32*)alloc(EE * sizeof(u32));
    u32* meta2 = (u32*)alloc(EE * sizeof(u32));
    int* cnt = (int*)alloc(NN * sizeof(int));
    int* cursor = (int*)alloc(NN * sizeof(int));
    int* chunk_sum = (int*)alloc(128 * sizeof(int));
    int* chunk_off = (int*)alloc(128 * sizeof(int));
    float* alpha = (float*)alloc(EE * sizeof(float));
    float* dinv1 = (float*)alloc(NN * sizeof(float));
    float* dinv2 = (float*)alloc(NN * sizeof(float));
    float* a_s = (float*)alloc(NN * sizeof(float));
    float* a_d = (float*)alloc(NN * sizeof(float));
    float* vs = (float*)alloc(HH * sizeof(float));
    float* vd = (float*)alloc(HH * sizeof(float));
    u16* Wt0 = (u16*)alloc(8192 * sizeof(u16));    // [128][64]
    u16* Wt1 = (u16*)alloc(16384 * sizeof(u16));   // [128][128]
    u16* Wt2 = (u16*)alloc(16384 * sizeof(u16));   // [128][128]
    u16* Wtr = (u16*)alloc(8192 * sizeof(u16));    // [64][128]
    u16* xb = (u16*)alloc((size_t)NN * FF * sizeof(u16));     // bf16(x)
    u16* xaggb = (u16*)alloc((size_t)NN * FF * sizeof(u16));  // bf16(Â x)
    u16* bufA = (u16*)alloc((size_t)NN * HH * sizeof(u16));
    u16* bufB = (u16*)alloc((size_t)NN * HH * sizeof(u16));

    hipMemsetAsync(cnt, 0, NN * sizeof(int), stream);

    // fused: edge count + x cast + weight transpose/cast + gemv
    build_k<<<(EE + PREP_ITEMS + 255) / 256, 256, 0, stream>>>(
        ecol, cnt, W0, W1, W2, Wr, Wg, att_src, att_dst, x,
        Wt0, Wt1, Wt2, Wtr, vs, vd, xb);
    chunksum_k<<<NCHUNK, 256, 0, stream>>>(cnt, chunk_sum, dinv1);
    chunkoff_k<<<1, 64, 0, stream>>>(chunk_sum, chunk_off, col_ptr);
    colptr_k<<<NCHUNK, 256, 0, stream>>>(cnt, chunk_off, col_ptr, cursor);
    fill_k<<<(EE + 255) / 256, 256, 0, stream>>>(erow, ecol, cursor, dinv1, meta1);

    int aggGrid = NN / 8;   // 12500, exact
    const int GG = 512;

    // layer 1: xagg = Â1 x ; y1 = relu(xagg@W0+b0)@W1 fused, + a_s/a_d
    aggx_k<<<aggGrid, 256, 0, stream>>>(xb, col_ptr, meta1, dinv1, xaggb);
    gemm1_k<<<GG, 256, 0, stream>>>(xaggb, Wt0, Wt1, b0, vs, vd, bufB, a_s, a_d);
    // attention
    attn_k<<<(NN + 31) / 32, 256, 0, stream>>>(col_ptr, meta1, a_s, a_d, alpha, dinv2);
    w2_k<<<(EE + 255) / 256, 256, 0, stream>>>(meta1, dinv2, alpha, meta2);
    // layer 2: x2 = agg(y1)
    agg2_k<<<aggGrid, 256, 0, stream>>>(bufB, col_ptr, meta2, dinv2, b1, bufA);
    // layer 3: y2 = x2@W2 ; x3 = agg(y2)
    mfma_gemm_k<HH, HH, false><<<GG, 256, 0, stream>>>(bufA, Wt2, nullptr, bufB);
    agg2_k<<<aggGrid, 256, 0, stream>>>(bufB, col_ptr, meta2, dinv2, b2, bufA);
    // readout
    mfma_gemm_k<HH, FF, true><<<GG, 256, 0, stream>>>(bufA, Wtr, br, out);
}

// Round 13
// 236.506 us; speedup vs baseline: 1.3896x; 1.0243x over previous
//
#include <hip/hip_runtime.h>
#include <hip/hip_bf16.h>
#include <hip/hip_fp16.h>
#include <math.h>

#define NN 100000
#define EE 600000
#define FF 64
#define HH 128
#define CHUNK 1024
#define NCHUNK ((NN + CHUNK - 1) / CHUNK)   // 98
#define NCHUNKS_M (NN / 16)                 // 6250 (exact)
#define PREP_ITEMS (NN * FF / 4 + 49280)

typedef unsigned short u16;
typedef unsigned int u32;
typedef __attribute__((ext_vector_type(8))) short bf16x8;
typedef __attribute__((ext_vector_type(4))) float f32x4;

__device__ __forceinline__ u16 f2bf(float f) {
    __hip_bfloat16 h = __float2bfloat16(f);
    return *(u16*)&h;
}
__device__ __forceinline__ float bf2f(u16 u) {
    unsigned int t = ((unsigned int)u) << 16;
    return *(float*)&t;
}
// meta pack: src in bits [31:15], fp16 weight (sign dropped, w>0) in [14:0]
__device__ __forceinline__ u32 enc_meta(int r, float w) {
    u16 hb = __half_as_ushort(__float2half(w));
    return ((u32)r << 15) | (hb & 0x7fffu);
}
__device__ __forceinline__ void dec_meta(u32 u, int& r, float& w) {
    r = (int)(u >> 15);
    w = __half2float(__ushort_as_half((u16)(u & 0x7fffu)));
}

// ---------------- fused: edge count (atomics) + weight/x prep ----------------

__global__ void build_k(const int* __restrict__ col, int* __restrict__ cnt,
                        const float* __restrict__ W0, const float* __restrict__ W1,
                        const float* __restrict__ W2, const float* __restrict__ Wr,
                        const float* __restrict__ Wg, const float* __restrict__ att_src,
                        const float* __restrict__ att_dst, const float* __restrict__ x,
                        u16* __restrict__ Wt0, u16* __restrict__ Wt1,
                        u16* __restrict__ Wt2, u16* __restrict__ Wtr,
                        float* __restrict__ vs, float* __restrict__ vd,
                        u16* __restrict__ xb) {
    int i = blockIdx.x * 256 + threadIdx.x;
    if (i < EE) {
        atomicAdd(&cnt[col[i]], 1);
        return;
    }
    i -= EE;
    if (i < NN * FF / 4) {          // cast x -> bf16
        float4 v = ((const float4*)x)[i];
        ushort4 o;
        o.x = f2bf(v.x); o.y = f2bf(v.y); o.z = f2bf(v.z); o.w = f2bf(v.w);
        ((ushort4*)xb)[i] = o;
        return;
    }
    i -= NN * FF / 4;
    if (i < 8192) {                 // Wt0: [128][64] from W0[64][128]
        int n = i >> 6, k = i & 63;
        Wt0[i] = f2bf(W0[k * 128 + n]);
        return;
    }
    i -= 8192;
    if (i < 16384) {                // Wt1: [128][128]
        int n = i >> 7, k = i & 127;
        Wt1[i] = f2bf(W1[k * 128 + n]);
        return;
    }
    i -= 16384;
    if (i < 16384) {                // Wt2: [128][128]
        int n = i >> 7, k = i & 127;
        Wt2[i] = f2bf(W2[k * 128 + n]);
        return;
    }
    i -= 16384;
    if (i < 8192) {                 // Wtr: [64][128] from Wr[128][64]
        int n = i >> 7, k = i & 127;
        Wtr[i] = f2bf(Wr[k * 64 + n]);
        return;
    }
    i -= 8192;
    if (i < HH) {                   // gemv: vs/vd = Wg @ att_{src,dst}
        float s1 = 0.f, s2 = 0.f;
        for (int j = 0; j < HH; j++) {
            float w = Wg[i * HH + j];
            s1 += w * att_src[j];
            s2 += w * att_dst[j];
        }
        vs[i] = s1;
        vd[i] = s2;
    }
}

// chunk sums + dinv1 fused
__global__ void chunksum_k(const int* __restrict__ cnt, int* __restrict__ chunk_sum,
                           float* __restrict__ dinv1) {
    int b = blockIdx.x, t = threadIdx.x;
    int base = b * CHUNK + t * 4;
    int s = 0;
    #pragma unroll
    for (int i = 0; i < 4; i++) {
        int idx = base + i;
        if (idx < NN) {
            int cv = cnt[idx];
            s += cv;
            dinv1[idx] = rsqrtf((float)cv + 1.0f);
        }
    }
    __shared__ int sm[4];
    for (int d = 32; d > 0; d >>= 1) s += __shfl_down(s, d);
    if ((t & 63) == 0) sm[t >> 6] = s;
    __syncthreads();
    if (t == 0) chunk_sum[b] = sm[0] + sm[1] + sm[2] + sm[3];
}

// col_ptr + cursor; chunk offset computed in-block (98 serial adds)
__global__ void colptr_k(const int* __restrict__ cnt, const int* __restrict__ chunk_sum,
                         int* __restrict__ col_ptr, int* __restrict__ cursor) {
    int b = blockIdx.x, t = threadIdx.x;
    __shared__ int base_off;
    if (t == 0) {
        int run = 0;
        for (int i = 0; i < b; i++) run += chunk_sum[i];
        base_off = run;
        if (b == 0) col_ptr[NN] = EE;
    }
    int base = b * CHUNK + t * 4;
    int c[4]; int tot = 0;
    #pragma unroll
    for (int i = 0; i < 4; i++) { int idx = base + i; c[i] = (idx < NN) ? cnt[idx] : 0; tot += c[i]; }
    __shared__ int s[256];
    s[t] = tot;
    __syncthreads();
    for (int d = 1; d < 256; d <<= 1) {
        int v = (t >= d) ? s[t - d] : 0;
        __syncthreads();
        s[t] += v;
        __syncthreads();
    }
    int excl = s[t] - tot;
    int off = base_off + excl;
    int pre = 0;
    #pragma unroll
    for (int i = 0; i < 4; i++) {
        int idx = base + i;
        if (idx < NN) {
            col_ptr[idx] = off + pre;
            cursor[idx] = off + pre;
        }
        pre += c[i];
    }
}

// fill CSR: single 4B scatter meta1 = enc(src, dinv1[r]*dinv1[c])
__global__ void fill_k(const int* __restrict__ row, const int* __restrict__ col,
                       int* __restrict__ cursor, const float* __restrict__ dinv1,
                       u32* __restrict__ meta1) {
    int e = blockIdx.x * 256 + threadIdx.x;
    if (e < EE) {
        int r = row[e], c = col[e];
        int slot = atomicAdd(&cursor[c], 1);
        meta1[slot] = enc_meta(r, dinv1[r] * dinv1[c]);
    }
}

// ---------------- layer-1 aggregate: 2 nodes/wave, 4 groups x 8 lanes x 2 streams ----------------

__global__ __launch_bounds__(256, 8) void aggx_k(
    const u16* __restrict__ xb, const int* __restrict__ col_ptr, const u32* __restrict__ meta1,
    const float* __restrict__ dinv1, u16* __restrict__ xout) {
    int wid = threadIdx.x >> 6, lane = threadIdx.x & 63;
    int sub = lane >> 5;
    int c = blockIdx.x * 8 + wid * 2 + sub;
    int hl = lane & 31;
    int g = hl >> 3;             // group 0..3
    int ch = (hl & 7) << 3;      // channel base 0,8,...,56
    int beg = col_ptr[c], end = col_ptr[c + 1];
    float acc[8] = {};

    int pA = beg + g, pB = pA + 4;
    int rA = 0, rB = 0; float wA = 0.f, wB = 0.f;
    if (pA < end) dec_meta(meta1[pA], rA, wA);
    if (pB < end) dec_meta(meta1[pB], rB, wB);
    while (pA < end) {
        bool hb = pB < end;
        bf16x8 vA = *(const bf16x8*)&xb[(size_t)rA * FF + ch];
        bf16x8 vB;
        if (hb) vB = *(const bf16x8*)&xb[(size_t)rB * FF + ch];
        int pA2 = pA + 8, pB2 = pB + 8;
        int rA2 = 0, rB2 = 0; float wA2 = 0.f, wB2 = 0.f;
        if (pA2 < end) dec_meta(meta1[pA2], rA2, wA2);
        if (pB2 < end) dec_meta(meta1[pB2], rB2, wB2);
        #pragma unroll
        for (int j = 0; j < 8; j++) acc[j] = fmaf(bf2f((u16)vA[j]), wA, acc[j]);
        if (hb) {
            #pragma unroll
            for (int j = 0; j < 8; j++) acc[j] = fmaf(bf2f((u16)vB[j]), wB, acc[j]);
        }
        pA = pA2; pB = pB2; rA = rA2; rB = rB2; wA = wA2; wB = wB2;
    }
    // combine 4 groups within half-wave (xor 8, 16)
    #pragma unroll
    for (int j = 0; j < 8; j++) {
        acc[j] += __shfl_xor(acc[j], 8);
        acc[j] += __shfl_xor(acc[j], 16);
    }

    if (g == 0) {
        bf16x8 v = *(const bf16x8*)&xb[(size_t)c * FF + ch];
        float dc = dinv1[c];
        float ws = dc * dc;
        bf16x8 o;
        #pragma unroll
        for (int j = 0; j < 8; j++) {
            float t = fmaf(bf2f((u16)v[j]), ws, acc[j]);
            o[j] = (short)f2bf(t);
        }
        *(bf16x8*)&xout[(size_t)c * FF + ch] = o;
    }
}

// ---------------- GEMM1 fused: y1 = (relu(xagg@W0+b0)) @ W1, plus a_s/a_d ----------------

__global__ __launch_bounds__(256) void gemm1_k(const u16* __restrict__ A,
                                               const u16* __restrict__ Wt0,
                                               const u16* __restrict__ Wt1,
                                               const float* __restrict__ bias,
                                               const float* __restrict__ vs, const float* __restrict__ vd,
                                               u16* __restrict__ Y, float* __restrict__ a_s,
                                               float* __restrict__ a_d) {
    constexpr int K = FF, N = HH, KK = K / 32, NT = N / 16, KK2 = HH / 32;
    constexpr int LSTRIDE = 136;
    __shared__ u16 lds[4][16 * LSTRIDE];
    int lane = threadIdx.x & 63, wid = threadIdx.x >> 6;
    int l15 = lane & 15, l4 = lane >> 4;
    int wg = blockIdx.x * 4 + wid;
    int nwaves = gridDim.x * 4;
    u16* myl = &lds[wid][0];

    bf16x8 a_frag[KK][NT];   // W0t fragments resident
    #pragma unroll
    for (int kk = 0; kk < KK; kk++)
        #pragma unroll
        for (int nt = 0; nt < NT; nt++)
            a_frag[kk][nt] = *(const bf16x8*)&Wt0[(size_t)(nt * 16 + l15) * K + kk * 32 + l4 * 8];

    for (int ch = wg; ch < NCHUNKS_M; ch += nwaves) {
        int row = ch * 16 + l15;
        bf16x8 b_frag[KK];
        #pragma unroll
        for (int kk = 0; kk < KK; kk++)
            b_frag[kk] = *(const bf16x8*)&A[(size_t)row * K + kk * 32 + l4 * 8];
        f32x4 acc[NT] = {};
        #pragma unroll
        for (int kk = 0; kk < KK; kk++)
            #pragma unroll
            for (int nt = 0; nt < NT; nt++)
                acc[nt] = __builtin_amdgcn_mfma_f32_16x16x32_bf16(a_frag[kk][nt], b_frag[kk],
                                                                  acc[nt], 0, 0, 0);
        float s1 = 0.f, s2 = 0.f;
        #pragma unroll
        for (int nt = 0; nt < NT; nt++) {
            f32x4 b4 = *(const f32x4*)&bias[nt * 16 + l4 * 4];
            f32x4 v4 = *(const f32x4*)&vs[nt * 16 + l4 * 4];
            f32x4 d4 = *(const f32x4*)&vd[nt * 16 + l4 * 4];
            float o0 = fmaxf(acc[nt][0] + b4[0], 0.f);
            float o1 = fmaxf(acc[nt][1] + b4[1], 0.f);
            float o2 = fmaxf(acc[nt][2] + b4[2], 0.f);
            float o3 = fmaxf(acc[nt][3] + b4[3], 0.f);
            ushort4 o;
            o.x = f2bf(o0); o.y = f2bf(o1); o.z = f2bf(o2); o.w = f2bf(o3);
            *(ushort4*)&myl[l15 * LSTRIDE + nt * 16 + l4 * 4] = o;
            s1 += o0 * v4[0] + o1 * v4[1] + o2 * v4[2] + o3 * v4[3];
            s2 += o0 * d4[0] + o1 * d4[1] + o2 * d4[2] + o3 * d4[3];
        }
        s1 += __shfl_xor(s1, 16); s1 += __shfl_xor(s1, 32);
        s2 += __shfl_xor(s2, 16); s2 += __shfl_xor(s2, 32);
        if (l4 == 0) {
            a_s[row] = s1;
            a_d[row] = s2;
        }
        // second GEMM: read x1 chunk back as B-fragments, multiply by W1t
        bf16x8 b2[KK2];
        #pragma unroll
        for (int kk2 = 0; kk2 < KK2; kk2++)
            b2[kk2] = *(const bf16x8*)&myl[l15 * LSTRIDE + kk2 * 32 + l4 * 8];
        f32x4 acc2[NT] = {};
        #pragma unroll
        for (int kk2 = 0; kk2 < KK2; kk2++)
            #pragma unroll
            for (int nt = 0; nt < NT; nt++) {
                bf16x8 w1f = *(const bf16x8*)&Wt1[(size_t)(nt * 16 + l15) * HH + kk2 * 32 + l4 * 8];
                acc2[nt] = __builtin_amdgcn_mfma_f32_16x16x32_bf16(w1f, b2[kk2], acc2[nt], 0, 0, 0);
            }
        #pragma unroll
        for (int nt = 0; nt < NT; nt++) {
            ushort4 o;
            o.x = f2bf(acc2[nt][0]);
            o.y = f2bf(acc2[nt][1]);
            o.z = f2bf(acc2[nt][2]);
            o.w = f2bf(acc2[nt][3]);
            *(ushort4*)&Y[(size_t)row * HH + nt * 16 + l4 * 4] = o;
        }
    }
}

// ---------------- attention: 8 lanes per node, online softmax ----------------

__global__ __launch_bounds__(256) void attn_k(const int* __restrict__ col_ptr,
                                              const u32* __restrict__ meta1,
                                              const float* __restrict__ a_s,
                                              const float* __restrict__ a_d,
                                              float* __restrict__ alpha,
                                              float* __restrict__ dinv2) {
    int lane = threadIdx.x & 63, wid = threadIdx.x >> 6;
    int grp = lane >> 3, idx = lane & 7;
    int c = blockIdx.x * 32 + wid * 8 + grp;
    if (c >= NN) return;
    int beg = col_ptr[c], end = col_ptr[c + 1];
    float ad = a_d[c];
    float es = a_s[c] + ad;
    es = (es > 0.f) ? es : 0.2f * es;
    float m = (idx == 0) ? es : -1e30f;
    float s = (idx == 0) ? 1.f : 0.f;
    for (int p = beg + idx; p < end; p += 8) {
        float e = a_s[meta1[p] >> 15] + ad;
        e = (e > 0.f) ? e : 0.2f * e;
        alpha[p] = e;
        float mn = fmaxf(m, e);
        s = s * expf(m - mn) + expf(e - mn);
        m = mn;
    }
    #pragma unroll
    for (int d = 1; d < 8; d <<= 1) {
        float mo = __shfl_xor(m, d);
        float so = __shfl_xor(s, d);
        float mn = fmaxf(m, mo);
        s = s * expf(m - mn) + so * expf(mo - mn);
        m = mn;
    }
    float inv = 1.f / s;
    float aself = expf(es - m) * inv;
    float d2 = rsqrtf(2.f - aself);
    if (idx == 0) dinv2[c] = d2;
    float sc = inv * d2;
    for (int p = beg + idx; p < end; p += 8)
        alpha[p] = expf(alpha[p] - m) * sc;
}

// meta2[p] = enc(src, alpha[p] * dinv2[src])
__global__ void w2_k(const u32* __restrict__ meta1, const float* __restrict__ dinv2,
                     const float* __restrict__ alpha, u32* __restrict__ meta2) {
    int p = blockIdx.x * 256 + threadIdx.x;
    if (p < EE) {
        u32 u = meta1[p];
        int r = (int)(u >> 15);
        float w = alpha[p] * dinv2[r];
        u16 hb = __half_as_ushort(__float2half(w));
        meta2[p] = (u & 0xffff8000u) | (hb & 0x7fffu);
    }
}

// ---------------- fused aggregate + GEMM: y = (relu-agg(xw)+bias) @ Wt ----------------
// Block = 16 dst nodes. Phase 1: 16 lanes/node, 3-stream gather pipeline; x-row
// (bf16) lands in a 16x136 LDS tile. Phase 2: 4 waves compute the 16x128 @ 128xNOUT
// MFMA GEMM (wave = NOUT/64 n-tiles) and write y (bf16) or out (f32 + bias_out).

template <int NOUT, bool OUTF32>
__global__ __launch_bounds__(256, 8) void agg_gemm_k(
    const u16* __restrict__ xw, const int* __restrict__ col_ptr, const u32* __restrict__ meta,
    const float* __restrict__ dinv2, const float* __restrict__ bias_in,
    const u16* __restrict__ Wt, const float* __restrict__ bias_out, void* __restrict__ Y_) {
    constexpr int KK2 = HH / 32;        // 4
    constexpr int NT = NOUT / 16;       // 8 or 4
    constexpr int NT_W = NT / 4;        // n-tiles per wave: 2 or 1
    constexpr int LSTRIDE = 136;
    __shared__ u16 lds[16 * LSTRIDE];
    int tid = threadIdx.x;
    int lane = tid & 63, wid = tid >> 6;
    int node = tid >> 4;                // 0..15
    int ch = (tid & 15) << 3;           // channel base 0..120
    int cbase = blockIdx.x * 16;
    int c = cbase + node;
    int beg = col_ptr[c], end = col_ptr[c + 1];
    float acc[8] = {};

    // phase 1: 3-stream gather (stride 3), each lane owns 8 channels
    int pA = beg, pB = beg + 1, pC = beg + 2;
    int rA = 0, rB = 0, rC = 0; float wA = 0.f, wB = 0.f, wC = 0.f;
    if (pA < end) dec_meta(meta[pA], rA, wA);
    if (pB < end) dec_meta(meta[pB], rB, wB);
    if (pC < end) dec_meta(meta[pC], rC, wC);
    while (pA < end) {
        bool hb = pB < end, hc = pC < end;
        bf16x8 vA = *(const bf16x8*)&xw[(size_t)rA * HH + ch];
        bf16x8 vB, vC;
        if (hb) vB = *(const bf16x8*)&xw[(size_t)rB * HH + ch];
        if (hc) vC = *(const bf16x8*)&xw[(size_t)rC * HH + ch];
        int pA2 = pA + 3, pB2 = pB + 3, pC2 = pC + 3;
        int rA2 = 0, rB2 = 0, rC2 = 0; float wA2 = 0.f, wB2 = 0.f, wC2 = 0.f;
        if (pA2 < end) dec_meta(meta[pA2], rA2, wA2);
        if (pB2 < end) dec_meta(meta[pB2], rB2, wB2);
        if (pC2 < end) dec_meta(meta[pC2], rC2, wC2);
        #pragma unroll
        for (int j = 0; j < 8; j++) acc[j] = fmaf(bf2f((u16)vA[j]), wA, acc[j]);
        if (hb) {
            #pragma unroll
            for (int j = 0; j < 8; j++) acc[j] = fmaf(bf2f((u16)vB[j]), wB, acc[j]);
        }
        if (hc) {
            #pragma unroll
            for (int j = 0; j < 8; j++) acc[j] = fmaf(bf2f((u16)vC[j]), wC, acc[j]);
        }
        pA = pA2; pB = pB2; pC = pC2;
        rA = rA2; rB = rB2; rC = rC2;
        wA = wA2; wB = wB2; wC = wC2;
    }
    {   // self loop + bias_in + relu -> LDS row (bf16)
        bf16x8 v = *(const bf16x8*)&xw[(size_t)c * HH + ch];
        float dc = dinv2[c];
        float ws = dc * dc;
        f32x4 b4a = *(const f32x4*)&bias_in[ch];
        f32x4 b4b = *(const f32x4*)&bias_in[ch + 4];
        bf16x8 o;
        #pragma unroll
        for (int j = 0; j < 8; j++) {
            float bj = (j < 4) ? b4a[j] : b4b[j - 4];
            float t = fmaxf(fmaf(bf2f((u16)v[j]), ws, acc[j]) + bj, 0.f);
            o[j] = (short)f2bf(t);
        }
        *(bf16x8*)&lds[node * LSTRIDE + ch] = o;
    }
    __syncthreads();

    // phase 2: MFMA GEMM, wave wid handles n-tiles [wid*NT_W, (wid+1)*NT_W)
    int l15 = lane & 15, l4 = lane >> 4;
    bf16x8 b2[KK2];
    #pragma unroll
    for (int kk2 = 0; kk2 < KK2; kk2++)
        b2[kk2] = *(const bf16x8*)&lds[l15 * LSTRIDE + kk2 * 32 + l4 * 8];
    int row = cbase + l15;
    #pragma unroll
    for (int ntw = 0; ntw < NT_W; ntw++) {
        int nt = wid * NT_W + ntw;
        f32x4 acc2 = {};
        #pragma unroll
        for (int kk2 = 0; kk2 < KK2; kk2++) {
            bf16x8 wf = *(const bf16x8*)&Wt[(size_t)(nt * 16 + l15) * HH + kk2 * 32 + l4 * 8];
            acc2 = __builtin_amdgcn_mfma_f32_16x16x32_bf16(wf, b2[kk2], acc2, 0, 0, 0);
        }
        int col = nt * 16 + l4 * 4;
        if (OUTF32) {
            float4 o;
            f32x4 bo = *(const f32x4*)&bias_out[col];
            o.x = acc2[0] + bo[0];
            o.y = acc2[1] + bo[1];
            o.z = acc2[2] + bo[2];
            o.w = acc2[3] + bo[3];
            *(float4*)&((float*)Y_)[(size_t)row * NOUT + col] = o;
        } else {
            ushort4 o;
            o.x = f2bf(acc2[0]);
            o.y = f2bf(acc2[1]);
            o.z = f2bf(acc2[2]);
            o.w = f2bf(acc2[3]);
            *(ushort4*)&((u16*)Y_)[(size_t)row * NOUT + col] = o;
        }
    }
}

// ---------------- launch ----------------

extern "C" void kernel_launch(void* const* d_in, const int* in_sizes, int n_in,
                              void* d_out, int out_size, void* d_ws, size_t ws_size,
                              hipStream_t stream) {
    const float* x = (const float*)d_in[0];
    const int* eidx = (const int*)d_in[1];     // [2][E]: row, col
    const float* W0 = (const float*)d_in[3];
    const float* b0 = (const float*)d_in[4];
    const float* Wg = (const float*)d_in[5];
    const float* att_src = (const float*)d_in[6];
    const float* att_dst = (const float*)d_in[7];
    const float* W1 = (const float*)d_in[8];
    const float* b1 = (const float*)d_in[9];
    const float* W2 = (const float*)d_in[10];
    const float* b2 = (const float*)d_in[11];
    const float* Wr = (const float*)d_in[12];
    const float* br = (const float*)d_in[13];
    float* out = (float*)d_out;

    const int* erow = eidx;
    const int* ecol = eidx + EE;

    char* p = (char*)d_ws;
    auto alloc = [&](size_t bytes) {
        void* r = (void*)p;
        p += (bytes + 255) & ~(size_t)255;
        return r;
    };
    int* col_ptr = (int*)alloc((NN + 1) * sizeof(int));
    u32* meta1 = (u32*)alloc(EE * sizeof(u32));
    u32* meta2 = (u32*)alloc(EE * sizeof(u32));
    int* cnt = (int*)alloc(NN * sizeof(int));
    int* cursor = (int*)alloc(NN * sizeof(int));
    int* chunk_sum = (int*)alloc(128 * sizeof(int));
    float* alpha = (float*)alloc(EE * sizeof(float));
    float* dinv1 = (float*)alloc(NN * sizeof(float));
    float* dinv2 = (float*)alloc(NN * sizeof(float));
    float* a_s = (float*)alloc(NN * sizeof(float));
    float* a_d = (float*)alloc(NN * sizeof(float));
    float* vs = (float*)alloc(HH * sizeof(float));
    float* vd = (float*)alloc(HH * sizeof(float));
    u16* Wt0 = (u16*)alloc(8192 * sizeof(u16));    // [128][64]
    u16* Wt1 = (u16*)alloc(16384 * sizeof(u16));   // [128][128]
    u16* Wt2 = (u16*)alloc(16384 * sizeof(u16));   // [128][128]
    u16* Wtr = (u16*)alloc(8192 * sizeof(u16));    // [64][128]
    u16* xb = (u16*)alloc((size_t)NN * FF * sizeof(u16));     // bf16(x)
    u16* xaggb = (u16*)alloc((size_t)NN * FF * sizeof(u16));  // bf16(Â x)
    u16* bufA = (u16*)alloc((size_t)NN * HH * sizeof(u16));
    u16* bufB = (u16*)alloc((size_t)NN * HH * sizeof(u16));

    hipMemsetAsync(cnt, 0, NN * sizeof(int), stream);

    // fused: edge count + x cast + weight transpose/cast + gemv
    build_k<<<(EE + PREP_ITEMS + 255) / 256, 256, 0, stream>>>(
        ecol, cnt, W0, W1, W2, Wr, Wg, att_src, att_dst, x,
        Wt0, Wt1, Wt2, Wtr, vs, vd, xb);
    chunksum_k<<<NCHUNK, 256, 0, stream>>>(cnt, chunk_sum, dinv1);
    colptr_k<<<NCHUNK, 256, 0, stream>>>(cnt, chunk_sum, col_ptr, cursor);
    fill_k<<<(EE + 255) / 256, 256, 0, stream>>>(erow, ecol, cursor, dinv1, meta1);

    int aggGrid = NN / 8;   // 12500, exact
    const int GG = 512;

    // layer 1: xagg = Â1 x ; y1 = relu(xagg@W0+b0)@W1 fused, + a_s/a_d
    aggx_k<<<aggGrid, 256, 0, stream>>>(xb, col_ptr, meta1, dinv1, xaggb);
    gemm1_k<<<GG, 256, 0, stream>>>(xaggb, Wt0, Wt1, b0, vs, vd, bufB, a_s, a_d);
    // attention
    attn_k<<<(NN + 31) / 32, 256, 0, stream>>>(col_ptr, meta1, a_s, a_d, alpha, dinv2);
    w2_k<<<(EE + 255) / 256, 256, 0, stream>>>(meta1, dinv2, alpha, meta2);
    // layer 2+3 fused: y2 = (relu-agg(y1)+b1)@W2
    agg_gemm_k<HH, false><<<NCHUNKS_M, 256, 0, stream>>>(bufB, col_ptr, meta2, dinv2, b1,
                                                         Wt2, nullptr, bufA);
    // layer 3+readout fused: out = (relu-agg(y2)+b2)@Wr + br
    agg_gemm_k<FF, true><<<NCHUNKS_M, 256, 0, stream>>>(bufA, col_ptr, meta2, dinv2, b2,
                                                        Wtr, br, out);
}